// Round 11
// baseline (100.430 us; speedup 1.0000x reference)
//
#include <hip/hip_runtime.h>
#include <hip/hip_bf16.h>
#include <stdint.h>

typedef __attribute__((ext_vector_type(8))) short bf16x8;
typedef __attribute__((ext_vector_type(4))) float f32x4;
typedef __attribute__((ext_vector_type(16))) float f32x16;

#define MFMA16(a,b,c) __builtin_amdgcn_mfma_f32_16x16x32_bf16((a),(b),(c),0,0,0)
#define MFMA32(a,b,c) __builtin_amdgcn_mfma_f32_32x32x16_bf16((a),(b),(c),0,0,0)
#define AS1 __attribute__((address_space(1)))
#define AS3 __attribute__((address_space(3)))

__device__ inline short f2bf(float f) {
    union { __hip_bfloat16 h; short s; } u;
    u.h = __float2bfloat16(f);
    return u.s;
}
__device__ inline uint32_t pack_bf16(float a, float b) {
    union { __hip_bfloat16 h; uint16_t u; } ua, ub;
    ua.h = __float2bfloat16(a); ub.h = __float2bfloat16(b);
    return (uint32_t)ua.u | ((uint32_t)ub.u << 16);
}

// cross-half register exchange
#if __has_builtin(__builtin_amdgcn_permlane32_swap)
#define SWAP32(x, y, a, b) { auto _r = __builtin_amdgcn_permlane32_swap((a),(b),false,false); \
                             (x) = _r[0]; (y) = _r[1]; }
#else
#define SWAP32(x, y, a, b) { uint32_t _ta = __shfl_xor((uint32_t)(a),32); \
                             uint32_t _tb = __shfl_xor((uint32_t)(b),32); \
                             (x) = hh_ ? _tb : (a); (y) = hh_ ? (b) : _ta; }
#endif

// S' = S * scale * log2(e): fold into Wq so attention exp is native exp2.
#define QSCALE 0.12751879523879295f   // (1/sqrt(128)) * log2(e)

// ---------------------------------------------------------------------------
// Kernel 1: eff-weight mix -> COMPACTED bf16 W [3][768][512]; x f32 -> bf16;
// zero-fill of the K d>=64 region for zero heads ONLY (4 MB).
// Zero structure: for heads 4-7, eff == 0 for d>=64 -> W rows exactly zero ->
// K/Q/V[d>=64] exactly zero.  W compacted to 768 rows/proj.
// R10 post-mortem: per-lane-predicated global_load_lds is ILLEGAL (LDS dest
// is readfirstlane(base)+lane*16; masking lanes 0-7 shifts every write by
// +128B -> K garbage/NaN).  So K d>=64 is zero-FILLED here and staged
// unconditionally; V's skip is wave-uniform (safe); Q zeros are registers.
// ---------------------------------------------------------------------------
#define NW (8*128*512)        // 524288 logical W elements per projection
#define NWC (768*512)         // 393216 compacted W elements per projection
#define NX4 (8192*512/4)      // 1048576 float4 chunks of x
#define NZK 262144            // uint4 chunks of K zero region (16 heads)

__global__ void prep_kernel(const float* __restrict__ x,
                            const float* __restrict__ w,
                            const float* __restrict__ bK,
                            const float* __restrict__ bQ,
                            const float* __restrict__ bV,
                            short* __restrict__ xb,    // [8192][512]
                            short* __restrict__ W,     // [3][768][512] (K,Q,V)
                            short* __restrict__ qkv)
{
    const float w0 = w[0], w1 = w[1], w2 = w[2], w3 = w[3];
    const size_t HSTRIDE = (size_t)2048 * 128;
    const uint4 z4 = {0u, 0u, 0u, 0u};
    for (int i = blockIdx.x * blockDim.x + threadIdx.x; i < NW + NX4 + NZK;
         i += gridDim.x * blockDim.x) {
        if (i < NW) {
            int e = i & 511;
            int d = (i >> 9) & 127;
            int h = i >> 16;
            if (h >= 4 && d >= 64) continue;    // exactly-zero row: compacted out
            float eff = 0.f;
            if (h < 4) { eff += w2; if (d < 64 && e < 256) eff += w0; }
            if (d < 32 && e < 256) eff += w1;
            if (d < 64) eff += w3;
            int r = (h < 4) ? (h * 128 + d) : (512 + (h - 4) * 64 + d);
            int idx = r * 512 + e;
            W[idx]           = f2bf(eff * bK[i]);
            W[idx + NWC]     = f2bf(eff * bQ[i] * QSCALE);
            W[idx + 2*NWC]   = f2bf(eff * bV[i]);
        } else if (i < NW + NX4) {
            int j = i - NW;
            float4 v = ((const float4*)x)[j];
            short4 o;
            o.x = f2bf(v.x); o.y = f2bf(v.y); o.z = f2bf(v.z); o.w = f2bf(v.w);
            ((short4*)xb)[j] = o;
        } else {
            // K[t][d]: zero d 64..127 of every t row, zero heads only
            int z = i - NW - NX4;               // 0..262143
            int bhidx = z >> 14;                // 16 zero heads
            int rem = z & 16383;                // t*8 + ch
            int bh = (bhidx >> 2) * 8 + 4 + (bhidx & 3);
            int t = rem >> 3, ch = rem & 7;
            short* p = qkv + (size_t)bh * HSTRIDE + (size_t)t * 128 + 64 + ch * 8;
            *(uint4*)p = z4;
        }
    }
}

// ---------------------------------------------------------------------------
// Kernel 2: C[8192,2304] = xb[8192,512] @ W[2304,512]^T   (compacted W)
// 18 column-tiles (6/proj): u<4 = head u full; u=4 -> heads 4,5 (d<64);
// u=5 -> heads 6,7 (d<64).  -25% MFMA vs the 24-tile version.
// K,Q stored [bh][t][d]; V stored TRANSPOSED as [bh][d][t].
// LDS-repacked coalesced epilogue; bijective XCD grid swizzle (1152=8*144).
// ---------------------------------------------------------------------------
__global__ __launch_bounds__(256)
void proj_gemm(const short* __restrict__ A,    // [8192][512]
               const short* __restrict__ Bw,   // [2304][512]
               short* __restrict__ qkv)
{
    __shared__ short S[128 * 128];             // 32 KB: staging + repack
    short* As = S;                             // 16 KB
    short* Bs = S + 128 * 64;                  // 16 KB
    const int tid = threadIdx.x;
    const int lane = tid & 63;
    const int wave = tid >> 6;
    const int wr = wave >> 1, wc = wave & 1;
    const int l15 = lane & 15, lk = lane >> 4;

    // bijective XCD swizzle: 1152 blocks, 144 consecutive per XCD
    const int wg = (blockIdx.x & 7) * 144 + (blockIdx.x >> 3);
    const int bm = (wg / 18) * 128;
    const int tt = wg % 18;                    // global column tile 0..17
    const int bn = tt * 128;
    const int p = tt / 6;                      // projection 0=K,1=Q,2=V
    const int u = tt % 6;                      // within-proj tile

    char* Ab = (char*)As;
    char* Bb = (char*)Bs;
    char* Sb = (char*)S;
    f32x4 acc[4][4] = {};

    for (int k0 = 0; k0 < 512; k0 += 64) {
        __syncthreads();
#pragma unroll
        for (int i = 0; i < 4; ++i) {
            int c = i * 256 + tid;              // 0..1023, 16B chunk
            int lin = c * 16;                   // linear byte in 16 KB tile
            int row = lin >> 7;                 // 0..127
            int cof = ((lin & 127) ^ ((row & 7) << 4)) >> 1;   // shorts
            __builtin_amdgcn_global_load_lds(
                (const AS1 void*)(A + (size_t)(bm + row) * 512 + k0 + cof),
                (AS3 void*)(As + c * 8), 16, 0, 0);
            __builtin_amdgcn_global_load_lds(
                (const AS1 void*)(Bw + (size_t)(bn + row) * 512 + k0 + cof),
                (AS3 void*)(Bs + c * 8), 16, 0, 0);
        }
        __syncthreads();                        // drains vmcnt(0) (m97 pattern)
#pragma unroll
        for (int kk = 0; kk < 2; ++kk) {
            bf16x8 af[4], bfv[4];
#pragma unroll
            for (int mi = 0; mi < 4; ++mi) {
                int row = wr * 64 + mi * 16 + l15;
                af[mi] = *(const bf16x8*)(Ab + ((row * 128 + kk * 64 + lk * 16) ^ ((row & 7) << 4)));
            }
#pragma unroll
            for (int ni = 0; ni < 4; ++ni) {
                int row = wc * 64 + ni * 16 + l15;
                bfv[ni] = *(const bf16x8*)(Bb + ((row * 128 + kk * 64 + lk * 16) ^ ((row & 7) << 4)));
            }
#pragma unroll
            for (int mi = 0; mi < 4; ++mi)
#pragma unroll
                for (int ni = 0; ni < 4; ++ni)
                    acc[mi][ni] = MFMA16(af[mi], bfv[ni], acc[mi][ni]);
        }
    }

    // ---- epilogue: repack C-tile via LDS, store coalesced -----------------
    const int b = bm >> 11;
    const int tbase = bm & 2047;

    __syncthreads();                            // staging reads done
    if (p == 2) {
        // V: LDS T[dl][tl] (transpose), pack r-pairs (consecutive tl)
#pragma unroll
        for (int mi = 0; mi < 4; ++mi) {
#pragma unroll
            for (int ni = 0; ni < 4; ++ni) {
                int dl = wc * 64 + ni * 16 + l15;
                int tlb = wr * 64 + mi * 16 + lk * 4;
                int byte0 = (dl * 256 + tlb * 2) ^ ((dl & 7) << 4);
                *(uint32_t*)(Sb + byte0)     = pack_bf16(acc[mi][ni][0], acc[mi][ni][1]);
                *(uint32_t*)(Sb + byte0 + 4) = pack_bf16(acc[mi][ni][2], acc[mi][ni][3]);
            }
        }
    } else {
        // K/Q: LDS T[tl][dl]
#pragma unroll
        for (int mi = 0; mi < 4; ++mi) {
#pragma unroll
            for (int ni = 0; ni < 4; ++ni) {
                int dl = wc * 64 + ni * 16 + l15;
#pragma unroll
                for (int r = 0; r < 4; ++r) {
                    int tl = wr * 64 + mi * 16 + lk * 4 + r;
                    *(short*)(Sb + ((tl * 256 + dl * 2) ^ ((tl & 7) << 4))) = f2bf(acc[mi][ni][r]);
                }
            }
        }
    }
    __syncthreads();

#pragma unroll
    for (int i = 0; i < 8; ++i) {
        int c = i * 256 + tid;                  // 0..2047 16B chunks
        int row = c >> 4;
        uint4 v = *(const uint4*)(Sb + row * 256 + (((c & 15) * 16) ^ ((row & 7) << 4)));
        if (p == 2) {
            // row = d-index in tile, cols = t
            int head, drow;
            if (u < 4) { head = u;                         drow = row;      }
            else       { head = 4 + (u - 4) * 2 + (row >> 6); drow = row & 63; }
            short* dst = qkv + (size_t)2 * (32 * 2048 * 128)
                       + (size_t)(b * 8 + head) * 128 * 2048;
            *(uint4*)(dst + (size_t)drow * 2048 + tbase + (c & 15) * 8) = v;
        } else {
            // row = t, cols = d-index in tile
            int cc = c & 15;
            int head, dcol;
            if (u < 4) { head = u;                          dcol = cc * 8;       }
            else       { head = 4 + (u - 4) * 2 + (cc >> 3); dcol = (cc & 7) * 8; }
            short* dst = qkv + (size_t)p * (32 * 2048 * 128)
                       + (size_t)(b * 8 + head) * 2048 * 128;
            *(uint4*)(dst + (size_t)(tbase + row) * 128 + dcol) = v;
        }
    }
}

// ---------------------------------------------------------------------------
// Kernel 3: causal flash attention — R6 frame + phase overlap:
//  (a) PV's 16 V-fragment ds_reads issued BEFORE softmax; cross-half max/sum
//      via permlane32_swap (pure VALU, no LDS queue ops) so V-read latency
//      hides under the VALU softmax phase.
//  (b) zero heads (bh&7>=4): V d>=64 staging SKIPPED (predicate is the
//      compile-time unroll index -> WAVE-UNIFORM, legal for global_load_lds)
//      with LDS pre-zero per strip; Q d>=64 frags = register zeros; K is
//      staged UNCONDITIONALLY from the prep-zero-filled region (per-lane
//      predication of global_load_lds is illegal — R10's NaN root cause:
//      readfirstlane base + lane*16 shifts writes when lane 0 is masked).
// Frame (verified R6/R9): KVBLK=128 dbuf, hoisted staging offsets, 256
// blocks x 512 thr, strips a & 15-a (uniform 17 iters), bh%8=XCD, per-strip
// LDS flash combine.  Dynamic LDS 131072 B.  1 block/CU, 2 waves/SIMD.
// ---------------------------------------------------------------------------
__global__ __launch_bounds__(512, 2)
void attn_kernel(const short* __restrict__ qkv, float* __restrict__ out)
{
    extern __shared__ char smem[];
    const int tid = threadIdx.x, lane = tid & 63, wave = tid >> 6;
    const int l31 = lane & 31;
    const int hh_ = lane >> 5;

    const int bh = blockIdx.x & 31;             // bh%8 = XCD under round-robin
    const int a = blockIdx.x >> 5;              // 0..7
    const bool zh = ((bh & 7) >= 4);            // head with d>=64 == 0

    const int qc = wave & 3;                    // q sub-block (32 rows)
    const int kvh = wave >> 2;                  // kv half of staged 128-kv tile

    const size_t HSTRIDE = (size_t)2048 * 128;
    const short* Kp = qkv + (size_t)bh * HSTRIDE;                    // [t][d]
    const short* Qp = qkv + (size_t)32 * HSTRIDE + (size_t)bh * HSTRIDE;
    const short* Vp = qkv + (size_t)64 * HSTRIDE + (size_t)bh * HSTRIDE; // [d][t]

    // ---- hoisted staging offsets (tid-only; computed once) ----------------
    int koffs[4], voffs[4];
#pragma unroll
    for (int i = 0; i < 4; ++i) {
        int c = i * 512 + tid;                  // 0..2047, 16B chunk index
        int rk = c >> 4;                        // K row 0..127
        int kof = (((c * 16) & 255) ^ ((rk & 15) << 4)) >> 1;
        koffs[i] = rk * 128 + kof;              // + j0*128 at stage time
        int sub = c >> 10, cc = c & 1023;       // V subtile, chunk within
        int rv = cc >> 4;                       // pair-row 0..63
        int pp = ((cc * 16) & 255) ^ ((rv & 15) << 4);
        int d = 2 * rv + (pp >> 7);
        int t = (pp & 127) >> 1;
        voffs[i] = d * 2048 + sub * 64 + t;     // + j0 at stage time
    }

// V chunks with i_ odd hold pair-rows 32-63 (= d>=64).  For zh blocks the
// skip predicate is (i_&1): compile-time per unroll iteration -> the whole
// wave takes the same path (legal).  K loads are NEVER predicated.
#define STAGE128(J0, BUF) {                                                   \
        char* _b = smem + ((BUF) << 16);                                      \
        _Pragma("unroll")                                                     \
        for (int i_ = 0; i_ < 4; ++i_) {                                      \
            int c = i_ * 512 + tid;                                           \
            __builtin_amdgcn_global_load_lds(                                 \
                (const AS1 void*)(Kp + koffs[i_] + (J0) * 128),               \
                (AS3 void*)(_b + c * 16), 16, 0, 0);                          \
            if (!zh || !(i_ & 1))                                             \
                __builtin_amdgcn_global_load_lds(                             \
                    (const AS1 void*)(Vp + voffs[i_] + (J0)),                 \
                    (AS3 void*)(_b + 32768 + c * 16), 16, 0, 0);              \
        }                                                                     \
    }

    for (int sidx = 0; sidx < 2; ++sidx) {
        const int sp = sidx ? (15 - a) : a;     // strip index 0..15
        const int q0 = sp * 128;
        const int nt = sp + 1;                  // 128-kv tiles
        const int qwave = q0 + qc * 32;
        const int qglob = qwave + l31;

        __syncthreads();                        // LDS free (prev combine done)

        // zero heads: restore exact-zero V LDS regions (combine aliased them)
        if (zh) {
            const uint4 z4 = {0u, 0u, 0u, 0u};
#pragma unroll
            for (int bq = 0; bq < 2; ++bq) {
                char* _b = smem + (bq << 16);
#pragma unroll
                for (int i2 = 1; i2 < 4; i2 += 2) {
                    int c = i2 * 512 + tid;
                    *(uint4*)(_b + 32768 + c * 16) = z4;
                }
            }
            __syncthreads();                    // zeros visible to all waves
        }

        // Q B-operand frags (zero heads: d>=64 frags are register zeros)
        bf16x8 qf[8];
        {
            const short* qrow = Qp + (size_t)(q0 + qc * 32 + l31) * 128 + hh_ * 8;
            const bf16x8 zerov = {};
#pragma unroll
            for (int dblk = 0; dblk < 4; ++dblk)
                qf[dblk] = *(const bf16x8*)(qrow + dblk * 16);
            if (zh) {
                qf[4] = zerov; qf[5] = zerov; qf[6] = zerov; qf[7] = zerov;
            } else {
#pragma unroll
                for (int dblk = 4; dblk < 8; ++dblk)
                    qf[dblk] = *(const bf16x8*)(qrow + dblk * 16);
            }
        }

        float mrow = -1e30f, lrow = 0.f;
        f32x16 acco[4] = {};                    // O[q(reg)][dt*32 + l31]

        STAGE128(0, 0);                         // prologue: tile 0 -> buf 0
        asm volatile("s_waitcnt vmcnt(0)" ::: "memory");
        __builtin_amdgcn_sched_barrier(0);
        __builtin_amdgcn_s_barrier();           // tile 0 visible to all waves
        __builtin_amdgcn_sched_barrier(0);

        for (int jt = 0; jt < nt; ++jt) {
            const int j0 = jt << 7;
            if (jt + 1 < nt)
                STAGE128((jt + 1) << 7, (jt + 1) & 1);

            const int kv0 = j0 + kvh * 64;      // this wave's 64-kv window
            if (kv0 <= qwave + 31) {            // wave-uniform causal gate
                const char* Kb = smem + ((jt & 1) << 16);
                const char* Vb = Kb + 32768 + (kvh << 14);   // sub = kvh

                // S'^T = K Q'^T : lane pair (l, l^32) holds S'[kv][q=l31]
                f32x16 sacc[2] = {};
                __builtin_amdgcn_s_setprio(1);
#pragma unroll
                for (int dblk = 0; dblk < 8; ++dblk) {
#pragma unroll
                    for (int kvt = 0; kvt < 2; ++kvt) {
                        int krow = kvh * 64 + kvt * 32 + l31;
                        bf16x8 kf = *(const bf16x8*)(Kb + krow * 256 +
                            ((dblk * 32 + hh_ * 16) ^ ((krow & 15) << 4)));
                        sacc[kvt] = MFMA32(kf, qf[dblk], sacc[kvt]);
                    }
                }
                __builtin_amdgcn_s_setprio(0);

                // PV V-frags: ISSUE NOW — latency hides under the (lgkm-free)
                // softmax below.  +64 VGPR, occupancy is LDS-capped anyway.
                bf16x8 vf[4][4];
#pragma unroll
                for (int w = 0; w < 4; ++w) {
#pragma unroll
                    for (int dt = 0; dt < 4; ++dt) {
                        int d = dt * 32 + l31;
                        int r = d >> 1;
                        int inner = ((d & 1) << 7) + w * 32 + hh_ * 16;
                        vf[w][dt] = *(const bf16x8*)(Vb + r * 256 + (inner ^ ((r & 15) << 4)));
                    }
                }

                // causal mask: only the straddle tile
                if (kv0 + 63 > qwave) {
#pragma unroll
                    for (int kvt = 0; kvt < 2; ++kvt)
#pragma unroll
                        for (int r = 0; r < 16; ++r) {
                            int kvglob = kv0 + kvt * 32 + (r & 3) + 8 * (r >> 2) + 4 * hh_;
                            if (kvglob > qglob) sacc[kvt][r] = -1e30f;
                        }
                }

                // row max: in-lane tree + cross-half permlane (no LDS ops)
                float pmax = -1e30f;
#pragma unroll
                for (int kvt = 0; kvt < 2; ++kvt)
#pragma unroll
                    for (int r = 0; r < 16; r += 4) {
                        float a2 = fmaxf(sacc[kvt][r], sacc[kvt][r + 1]);
                        float b2 = fmaxf(sacc[kvt][r + 2], sacc[kvt][r + 3]);
                        pmax = fmaxf(pmax, fmaxf(a2, b2));
                    }
                {
                    uint32_t pa_ = __builtin_bit_cast(uint32_t, pmax), xx_, yy_;
                    SWAP32(xx_, yy_, pa_, pa_);
                    pmax = fmaxf(__builtin_bit_cast(float, xx_),
                                 __builtin_bit_cast(float, yy_));
                }

                // defer-max: rescale only when max grew by > 8 nats
                if (!__all(pmax - mrow <= 11.5416f)) {
                    float mn = fmaxf(mrow, pmax);
                    float alpha = __builtin_amdgcn_exp2f(mrow - mn);
                    mrow = mn;
                    lrow *= alpha;
#pragma unroll
                    for (int r = 0; r < 16; ++r) {
                        float ar = __shfl(alpha, (r & 3) + 8 * (r >> 2) + 4 * hh_);
#pragma unroll
                        for (int dt = 0; dt < 4; ++dt) acco[dt][r] *= ar;
                    }
                }

                // P = exp2(S' - m'), row sum, pack to bf16 pairs
                float psum = 0.f;
                uint32_t pkA[2][4], pkB[2][4];
#pragma unroll
                for (int kvt = 0; kvt < 2; ++kvt)
#pragma unroll
                    for (int sg = 0; sg < 4; ++sg) {
                        float p0 = __builtin_amdgcn_exp2f(sacc[kvt][4 * sg + 0] - mrow);
                        float p1 = __builtin_amdgcn_exp2f(sacc[kvt][4 * sg + 1] - mrow);
                        float p2 = __builtin_amdgcn_exp2f(sacc[kvt][4 * sg + 2] - mrow);
                        float p3 = __builtin_amdgcn_exp2f(sacc[kvt][4 * sg + 3] - mrow);
                        psum += (p0 + p1) + (p2 + p3);
                        pkA[kvt][sg] = pack_bf16(p0, p1);
                        pkB[kvt][sg] = pack_bf16(p2, p3);
                    }
                {
                    uint32_t pa_ = __builtin_bit_cast(uint32_t, psum), xx_, yy_;
                    SWAP32(xx_, yy_, pa_, pa_);
                    psum = __builtin_bit_cast(float, xx_) +
                           __builtin_bit_cast(float, yy_);
                }
                lrow += psum;

                // O += P V  (pure MFMA: V-frags already in registers)
                __builtin_amdgcn_s_setprio(1);
#pragma unroll
                for (int w = 0; w < 4; ++w) {   // 16-kv slot within 64-kv half
                    const int kvt = w >> 1, kbl = w & 1;
                    uint32_t r0, r1, r2, r3;
                    SWAP32(r0, r2, pkA[kvt][2 * kbl], pkA[kvt][2 * kbl + 1]);
                    SWAP32(r1, r3, pkB[kvt][2 * kbl], pkB[kvt][2 * kbl + 1]);
                    union { uint32_t u[4]; bf16x8 v; } pa;
                    pa.u[0] = r0; pa.u[1] = r1; pa.u[2] = r2; pa.u[3] = r3;
#pragma unroll
                    for (int dt = 0; dt < 4; ++dt)
                        acco[dt] = MFMA32(pa.v, vf[w][dt], acco[dt]);
                }
                __builtin_amdgcn_s_setprio(0);
            }

            if (jt + 1 < nt) {
                asm volatile("s_waitcnt vmcnt(0)" ::: "memory");  // tile jt+1 landed
                __builtin_amdgcn_sched_barrier(0);
                __builtin_amdgcn_s_barrier();   // publish tile jt+1, release buf
                __builtin_amdgcn_sched_barrier(0);
            }
        }

        // ---- intra-block flash combine: merge kv halves (waves w, w+4) ----
        __syncthreads();                        // all waves done reading LDS
        float* ex = (float*)smem;               // 4 chunks x 4096 f32 (64 KB)
        float* ml = (float*)(smem + 65536);     // 4 chunks x 64 x {m,l} (2 KB)
        if (kvh == 1) {
            float* dst = ex + qc * 4096;
#pragma unroll
            for (int dt = 0; dt < 4; ++dt)
#pragma unroll
                for (int r = 0; r < 16; ++r)
                    dst[(dt * 16 + r) * 64 + lane] = acco[dt][r];
            ml[qc * 128 + lane * 2 + 0] = mrow;
            ml[qc * 128 + lane * 2 + 1] = lrow;
        }
        __syncthreads();
        if (kvh == 0) {
            float m1 = ml[qc * 128 + lane * 2 + 0];
            float l1 = ml[qc * 128 + lane * 2 + 1];
            float M  = fmaxf(mrow, m1);
            float av = __builtin_amdgcn_exp2f(mrow - M);
            float bv = __builtin_amdgcn_exp2f(m1 - M);  // 0 if half empty
            float lf = lrow * av + l1 * bv;
            float sA = av / lf, sB = bv / lf;
            const float* src = ex + qc * 4096;
            const int bb = bh >> 3, hd = bh & 7;
#pragma unroll
            for (int r = 0; r < 16; ++r) {
                int ql = (r & 3) + 8 * (r >> 2) + 4 * hh_;
                float sa = __shfl(sA, ql);
                float sb = __shfl(sB, ql);
                int t = qwave + ql;
                float* o = out + (size_t)(bb * 2048 + t) * 1024 + hd * 128 + l31;
#pragma unroll
                for (int dt = 0; dt < 4; ++dt)
                    o[dt * 32] = acco[dt][r] * sa + src[(dt * 16 + r) * 64 + lane] * sb;
            }
        }
        // drain combine stores before next strip's staging/waits
        asm volatile("s_waitcnt vmcnt(0)" ::: "memory");
    }
#undef STAGE128
}

// ---------------------------------------------------------------------------
extern "C" void kernel_launch(void* const* d_in, const int* in_sizes, int n_in,
                              void* d_out, int out_size, void* d_ws, size_t ws_size,
                              hipStream_t stream) {
    const float* x  = (const float*)d_in[0];
    const float* w  = (const float*)d_in[1];
    const float* bK = (const float*)d_in[2];
    const float* bQ = (const float*)d_in[3];
    const float* bV = (const float*)d_in[4];

    // workspace layout (bytes): xb 8,388,608 | W 3,145,728 (uses 2,359,296) |
    // qkv 50,331,648
    short* xb  = (short*)d_ws;
    short* W   = (short*)((char*)d_ws + 8388608);
    short* qkv = (short*)((char*)d_ws + 8388608 + 3145728);
    float* out = (float*)d_out;

    // allow 128 KB dynamic LDS (idempotent; not a stream op, capture-safe)
    hipFuncSetAttribute((const void*)attn_kernel,
                        hipFuncAttributeMaxDynamicSharedMemorySize, 131072);

    prep_kernel<<<2048, 256, 0, stream>>>(x, w, bK, bQ, bV, xb, W, qkv);
    proj_gemm<<<64 * 18, 256, 0, stream>>>(xb, W, qkv);
    attn_kernel<<<256, 512, 131072, stream>>>(qkv, out);
}

// Round 12
// 98.799 us; speedup vs baseline: 1.0165x; 1.0165x over previous
//
#include <hip/hip_runtime.h>
#include <hip/hip_bf16.h>
#include <stdint.h>

typedef __attribute__((ext_vector_type(8))) short bf16x8;
typedef __attribute__((ext_vector_type(4))) float f32x4;
typedef __attribute__((ext_vector_type(16))) float f32x16;

#define MFMA16(a,b,c) __builtin_amdgcn_mfma_f32_16x16x32_bf16((a),(b),(c),0,0,0)
#define MFMA32(a,b,c) __builtin_amdgcn_mfma_f32_32x32x16_bf16((a),(b),(c),0,0,0)
#define AS1 __attribute__((address_space(1)))
#define AS3 __attribute__((address_space(3)))

__device__ inline short f2bf(float f) {
    union { __hip_bfloat16 h; short s; } u;
    u.h = __float2bfloat16(f);
    return u.s;
}
__device__ inline uint32_t pack_bf16(float a, float b) {
    union { __hip_bfloat16 h; uint16_t u; } ua, ub;
    ua.h = __float2bfloat16(a); ub.h = __float2bfloat16(b);
    return (uint32_t)ua.u | ((uint32_t)ub.u << 16);
}

// cross-half register exchange
#if __has_builtin(__builtin_amdgcn_permlane32_swap)
#define SWAP32(x, y, a, b) { auto _r = __builtin_amdgcn_permlane32_swap((a),(b),false,false); \
                             (x) = _r[0]; (y) = _r[1]; }
#else
#define SWAP32(x, y, a, b) { uint32_t _ta = __shfl_xor((uint32_t)(a),32); \
                             uint32_t _tb = __shfl_xor((uint32_t)(b),32); \
                             (x) = hh_ ? _tb : (a); (y) = hh_ ? (b) : _ta; }
#endif

// S' = S * scale * log2(e): fold into Wq so attention exp is native exp2.
#define QSCALE 0.12751879523879295f   // (1/sqrt(128)) * log2(e)

// ---------------------------------------------------------------------------
// Kernel 1: eff-weight mix -> COMPACTED bf16 W [3][768][512]; x f32 -> bf16;
// zero-fill of the structurally-zero qkv regions (R9-verified version).
// Zero structure: for heads 4-7, eff == 0 for d>=64 -> W rows exactly zero ->
// K/Q/V[d>=64] exactly zero.  W compacted to 768 rows/proj: heads 0-3 at
// r=h*128+d (full), heads 4-7 at r=512+(h-4)*64+d (d<64 only).  proj_gemm
// computes 18 column-tiles instead of 24 (-25% MFMA).  Dead qkv regions
// zero-filled HERE (bit-identical to what proj used to compute: +0.0).
// ---------------------------------------------------------------------------
#define NW (8*128*512)        // 524288 logical W elements per projection
#define NWC (768*512)         // 393216 compacted W elements per projection
#define NX4 (8192*512/4)      // 1048576 float4 chunks of x
#define NZ1 262144            // uint4 chunks per zero region (K / Q / V)

__global__ void prep_kernel(const float* __restrict__ x,
                            const float* __restrict__ w,
                            const float* __restrict__ bK,
                            const float* __restrict__ bQ,
                            const float* __restrict__ bV,
                            short* __restrict__ xb,    // [8192][512]
                            short* __restrict__ W,     // [3][768][512] (K,Q,V)
                            short* __restrict__ qkv)
{
    const float w0 = w[0], w1 = w[1], w2 = w[2], w3 = w[3];
    const size_t HSTRIDE = (size_t)2048 * 128;
    const uint4 zz = {0u, 0u, 0u, 0u};
    for (int i = blockIdx.x * blockDim.x + threadIdx.x; i < NW + NX4 + 3 * NZ1;
         i += gridDim.x * blockDim.x) {
        if (i < NW) {
            int e = i & 511;
            int d = (i >> 9) & 127;
            int h = i >> 16;
            if (h >= 4 && d >= 64) continue;    // exactly-zero row: compacted out
            float eff = 0.f;
            if (h < 4) { eff += w2; if (d < 64 && e < 256) eff += w0; }
            if (d < 32 && e < 256) eff += w1;
            if (d < 64) eff += w3;
            int r = (h < 4) ? (h * 128 + d) : (512 + (h - 4) * 64 + d);
            int idx = r * 512 + e;
            W[idx]           = f2bf(eff * bK[i]);
            W[idx + NWC]     = f2bf(eff * bQ[i] * QSCALE);
            W[idx + 2*NWC]   = f2bf(eff * bV[i]);
        } else if (i < NW + NX4) {
            int j = i - NW;
            float4 v = ((const float4*)x)[j];
            short4 o;
            o.x = f2bf(v.x); o.y = f2bf(v.y); o.z = f2bf(v.z); o.w = f2bf(v.w);
            ((short4*)xb)[j] = o;
        } else {
            int z = i - NW - NX4;               // 0 .. 3*NZ1-1
            int reg = z / NZ1;                  // 0=K, 1=Q, 2=V
            int zz_ = z - reg * NZ1;            // 0..262143
            int bhidx = zz_ >> 14;              // 16 zero heads
            int rem = zz_ & 16383;
            int bh = (bhidx >> 2) * 8 + 4 + (bhidx & 3);
            short* p;
            if (reg < 2) {
                // K/Q [t][d]: zero d 64..127 of every t row
                int t = rem >> 3, ch = rem & 7;
                p = qkv + (size_t)reg * 32 * HSTRIDE + (size_t)bh * HSTRIDE
                    + (size_t)t * 128 + 64 + ch * 8;
            } else {
                // V [d][t]: rows d 64..127 contiguous
                p = qkv + (size_t)64 * HSTRIDE + (size_t)bh * HSTRIDE
                    + (size_t)64 * 2048 + (size_t)rem * 8;
            }
            *(uint4*)p = zz;
        }
    }
}

// ---------------------------------------------------------------------------
// Kernel 2: C[8192,2304] = xb[8192,512] @ W[2304,512]^T   (compacted W)
// 18 column-tiles (6/proj): u<4 = head u full; u=4 -> heads 4,5 (d<64);
// u=5 -> heads 6,7 (d<64).  -25% MFMA vs the 24-tile version.
// K,Q stored [bh][t][d]; V stored TRANSPOSED as [bh][d][t].
// LDS-repacked coalesced epilogue; bijective XCD grid swizzle (1152=8*144).
// ---------------------------------------------------------------------------
__global__ __launch_bounds__(256)
void proj_gemm(const short* __restrict__ A,    // [8192][512]
               const short* __restrict__ Bw,   // [2304][512]
               short* __restrict__ qkv)
{
    __shared__ short S[128 * 128];             // 32 KB: staging + repack
    short* As = S;                             // 16 KB
    short* Bs = S + 128 * 64;                  // 16 KB
    const int tid = threadIdx.x;
    const int lane = tid & 63;
    const int wave = tid >> 6;
    const int wr = wave >> 1, wc = wave & 1;
    const int l15 = lane & 15, lk = lane >> 4;

    // bijective XCD swizzle: 1152 blocks, 144 consecutive per XCD
    const int wg = (blockIdx.x & 7) * 144 + (blockIdx.x >> 3);
    const int bm = (wg / 18) * 128;
    const int tt = wg % 18;                    // global column tile 0..17
    const int bn = tt * 128;
    const int p = tt / 6;                      // projection 0=K,1=Q,2=V
    const int u = tt % 6;                      // within-proj tile

    char* Ab = (char*)As;
    char* Bb = (char*)Bs;
    char* Sb = (char*)S;
    f32x4 acc[4][4] = {};

    for (int k0 = 0; k0 < 512; k0 += 64) {
        __syncthreads();
#pragma unroll
        for (int i = 0; i < 4; ++i) {
            int c = i * 256 + tid;              // 0..1023, 16B chunk
            int lin = c * 16;                   // linear byte in 16 KB tile
            int row = lin >> 7;                 // 0..127
            int cof = ((lin & 127) ^ ((row & 7) << 4)) >> 1;   // shorts
            __builtin_amdgcn_global_load_lds(
                (const AS1 void*)(A + (size_t)(bm + row) * 512 + k0 + cof),
                (AS3 void*)(As + c * 8), 16, 0, 0);
            __builtin_amdgcn_global_load_lds(
                (const AS1 void*)(Bw + (size_t)(bn + row) * 512 + k0 + cof),
                (AS3 void*)(Bs + c * 8), 16, 0, 0);
        }
        __syncthreads();                        // drains vmcnt(0) (m97 pattern)
#pragma unroll
        for (int kk = 0; kk < 2; ++kk) {
            bf16x8 af[4], bfv[4];
#pragma unroll
            for (int mi = 0; mi < 4; ++mi) {
                int row = wr * 64 + mi * 16 + l15;
                af[mi] = *(const bf16x8*)(Ab + ((row * 128 + kk * 64 + lk * 16) ^ ((row & 7) << 4)));
            }
#pragma unroll
            for (int ni = 0; ni < 4; ++ni) {
                int row = wc * 64 + ni * 16 + l15;
                bfv[ni] = *(const bf16x8*)(Bb + ((row * 128 + kk * 64 + lk * 16) ^ ((row & 7) << 4)));
            }
#pragma unroll
            for (int mi = 0; mi < 4; ++mi)
#pragma unroll
                for (int ni = 0; ni < 4; ++ni)
                    acc[mi][ni] = MFMA16(af[mi], bfv[ni], acc[mi][ni]);
        }
    }

    // ---- epilogue: repack C-tile via LDS, store coalesced -----------------
    const int b = bm >> 11;
    const int tbase = bm & 2047;

    __syncthreads();                            // staging reads done
    if (p == 2) {
        // V: LDS T[dl][tl] (transpose), pack r-pairs (consecutive tl)
#pragma unroll
        for (int mi = 0; mi < 4; ++mi) {
#pragma unroll
            for (int ni = 0; ni < 4; ++ni) {
                int dl = wc * 64 + ni * 16 + l15;
                int tlb = wr * 64 + mi * 16 + lk * 4;
                int byte0 = (dl * 256 + tlb * 2) ^ ((dl & 7) << 4);
                *(uint32_t*)(Sb + byte0)     = pack_bf16(acc[mi][ni][0], acc[mi][ni][1]);
                *(uint32_t*)(Sb + byte0 + 4) = pack_bf16(acc[mi][ni][2], acc[mi][ni][3]);
            }
        }
    } else {
        // K/Q: LDS T[tl][dl]
#pragma unroll
        for (int mi = 0; mi < 4; ++mi) {
#pragma unroll
            for (int ni = 0; ni < 4; ++ni) {
                int dl = wc * 64 + ni * 16 + l15;
#pragma unroll
                for (int r = 0; r < 4; ++r) {
                    int tl = wr * 64 + mi * 16 + lk * 4 + r;
                    *(short*)(Sb + ((tl * 256 + dl * 2) ^ ((tl & 7) << 4))) = f2bf(acc[mi][ni][r]);
                }
            }
        }
    }
    __syncthreads();

#pragma unroll
    for (int i = 0; i < 8; ++i) {
        int c = i * 256 + tid;                  // 0..2047 16B chunks
        int row = c >> 4;
        uint4 v = *(const uint4*)(Sb + row * 256 + (((c & 15) * 16) ^ ((row & 7) << 4)));
        if (p == 2) {
            // row = d-index in tile, cols = t
            int head, drow;
            if (u < 4) { head = u;                         drow = row;      }
            else       { head = 4 + (u - 4) * 2 + (row >> 6); drow = row & 63; }
            short* dst = qkv + (size_t)2 * (32 * 2048 * 128)
                       + (size_t)(b * 8 + head) * 128 * 2048;
            *(uint4*)(dst + (size_t)drow * 2048 + tbase + (c & 15) * 8) = v;
        } else {
            // row = t, cols = d-index in tile
            int cc = c & 15;
            int head, dcol;
            if (u < 4) { head = u;                          dcol = cc * 8;       }
            else       { head = 4 + (u - 4) * 2 + (cc >> 3); dcol = (cc & 7) * 8; }
            short* dst = qkv + (size_t)p * (32 * 2048 * 128)
                       + (size_t)(b * 8 + head) * 2048 * 128;
            *(uint4*)(dst + (size_t)(tbase + row) * 128 + dcol) = v;
        }
    }
}

// ---------------------------------------------------------------------------
// Kernel 3: causal flash attention — R6/R9-verified frame (59.1 us), with
// ONE micro-change kept from R11 (verified bit-identical there): the two
// per-iteration cross-half reductions (pmax, psum) use permlane32_swap
// (pure VALU, 1 instr) instead of __shfl_xor (ds_bpermute + lgkm wait).
// R11 post-mortem: vf-prefetch (+16 VGPR-held V-frags across softmax) and
// V-staging-skip both REGRESSED attn (59.1 -> 63.8); reverted.
// Frame: KVBLK=128 dbuf, hoisted staging offsets, 256 blocks x 512 thr,
// strips a & 15-a (uniform 17 iters), bh%8=XCD, per-strip LDS flash combine.
// Dynamic LDS 131072 B: 2 buffers x {K 32K | V 2x16K}. 1 block/CU.
// ---------------------------------------------------------------------------
__global__ __launch_bounds__(512, 2)
void attn_kernel(const short* __restrict__ qkv, float* __restrict__ out)
{
    extern __shared__ char smem[];
    const int tid = threadIdx.x, lane = tid & 63, wave = tid >> 6;
    const int l31 = lane & 31;
    const int hh_ = lane >> 5;

    const int bh = blockIdx.x & 31;             // bh%8 = XCD under round-robin
    const int a = blockIdx.x >> 5;              // 0..7

    const int qc = wave & 3;                    // q sub-block (32 rows)
    const int kvh = wave >> 2;                  // kv half of staged 128-kv tile

    const size_t HSTRIDE = (size_t)2048 * 128;
    const short* Kp = qkv + (size_t)bh * HSTRIDE;                    // [t][d]
    const short* Qp = qkv + (size_t)32 * HSTRIDE + (size_t)bh * HSTRIDE;
    const short* Vp = qkv + (size_t)64 * HSTRIDE + (size_t)bh * HSTRIDE; // [d][t]

    // ---- hoisted staging offsets (tid-only; computed once) ----------------
    int koffs[4], voffs[4];
#pragma unroll
    for (int i = 0; i < 4; ++i) {
        int c = i * 512 + tid;                  // 0..2047, 16B chunk index
        int rk = c >> 4;                        // K row 0..127
        int kof = (((c * 16) & 255) ^ ((rk & 15) << 4)) >> 1;
        koffs[i] = rk * 128 + kof;              // + j0*128 at stage time
        int sub = c >> 10, cc = c & 1023;       // V subtile, chunk within
        int rv = cc >> 4;                       // pair-row 0..63
        int pp = ((cc * 16) & 255) ^ ((rv & 15) << 4);
        int d = 2 * rv + (pp >> 7);
        int t = (pp & 127) >> 1;
        voffs[i] = d * 2048 + sub * 64 + t;     // + j0 at stage time
    }

#define STAGE128(J0, BUF) {                                                   \
        char* _b = smem + ((BUF) << 16);                                      \
        _Pragma("unroll")                                                     \
        for (int i_ = 0; i_ < 4; ++i_) {                                      \
            int c = i_ * 512 + tid;                                           \
            __builtin_amdgcn_global_load_lds(                                 \
                (const AS1 void*)(Kp + koffs[i_] + (J0) * 128),               \
                (AS3 void*)(_b + c * 16), 16, 0, 0);                          \
            __builtin_amdgcn_global_load_lds(                                 \
                (const AS1 void*)(Vp + voffs[i_] + (J0)),                     \
                (AS3 void*)(_b + 32768 + c * 16), 16, 0, 0);                  \
        }                                                                     \
    }

    for (int sidx = 0; sidx < 2; ++sidx) {
        const int sp = sidx ? (15 - a) : a;     // strip index 0..15
        const int q0 = sp * 128;
        const int nt = sp + 1;                  // 128-kv tiles
        const int qwave = q0 + qc * 32;
        const int qglob = qwave + l31;

        __syncthreads();                        // LDS free (prev combine done)

        // Q B-operand frags
        bf16x8 qf[8];
        {
            const short* qrow = Qp + (size_t)(q0 + qc * 32 + l31) * 128 + hh_ * 8;
#pragma unroll
            for (int dblk = 0; dblk < 8; ++dblk)
                qf[dblk] = *(const bf16x8*)(qrow + dblk * 16);
        }

        float mrow = -1e30f, lrow = 0.f;
        f32x16 acco[4] = {};                    // O[q(reg)][dt*32 + l31]

        STAGE128(0, 0);                         // prologue: tile 0 -> buf 0
        asm volatile("s_waitcnt vmcnt(0)" ::: "memory");
        __builtin_amdgcn_sched_barrier(0);
        __builtin_amdgcn_s_barrier();           // tile 0 visible to all waves
        __builtin_amdgcn_sched_barrier(0);

        for (int jt = 0; jt < nt; ++jt) {
            const int j0 = jt << 7;
            if (jt + 1 < nt)
                STAGE128((jt + 1) << 7, (jt + 1) & 1);

            const int kv0 = j0 + kvh * 64;      // this wave's 64-kv window
            if (kv0 <= qwave + 31) {            // wave-uniform causal gate
                const char* Kb = smem + ((jt & 1) << 16);
                const char* Vb = Kb + 32768 + (kvh << 14);   // sub = kvh

                // S'^T = K Q'^T : lane pair (l, l^32) holds S'[kv][q=l31]
                f32x16 sacc[2] = {};
                __builtin_amdgcn_s_setprio(1);
#pragma unroll
                for (int dblk = 0; dblk < 8; ++dblk) {
#pragma unroll
                    for (int kvt = 0; kvt < 2; ++kvt) {
                        int krow = kvh * 64 + kvt * 32 + l31;
                        bf16x8 kf = *(const bf16x8*)(Kb + krow * 256 +
                            ((dblk * 32 + hh_ * 16) ^ ((krow & 15) << 4)));
                        sacc[kvt] = MFMA32(kf, qf[dblk], sacc[kvt]);
                    }
                }
                __builtin_amdgcn_s_setprio(0);

                // causal mask: only the straddle tile
                if (kv0 + 63 > qwave) {
#pragma unroll
                    for (int kvt = 0; kvt < 2; ++kvt)
#pragma unroll
                        for (int r = 0; r < 16; ++r) {
                            int kvglob = kv0 + kvt * 32 + (r & 3) + 8 * (r >> 2) + 4 * hh_;
                            if (kvglob > qglob) sacc[kvt][r] = -1e30f;
                        }
                }

                // row max: in-lane tree + cross-half permlane (pure VALU)
                float pmax = -1e30f;
#pragma unroll
                for (int kvt = 0; kvt < 2; ++kvt)
#pragma unroll
                    for (int r = 0; r < 16; r += 4) {
                        float a2 = fmaxf(sacc[kvt][r], sacc[kvt][r + 1]);
                        float b2 = fmaxf(sacc[kvt][r + 2], sacc[kvt][r + 3]);
                        pmax = fmaxf(pmax, fmaxf(a2, b2));
                    }
                {
                    uint32_t pa_ = __builtin_bit_cast(uint32_t, pmax), xx_, yy_;
                    SWAP32(xx_, yy_, pa_, pa_);
                    pmax = fmaxf(__builtin_bit_cast(float, xx_),
                                 __builtin_bit_cast(float, yy_));
                }

                // defer-max: rescale only when max grew by > 8 nats
                if (!__all(pmax - mrow <= 11.5416f)) {
                    float mn = fmaxf(mrow, pmax);
                    float alpha = __builtin_amdgcn_exp2f(mrow - mn);
                    mrow = mn;
                    lrow *= alpha;
#pragma unroll
                    for (int r = 0; r < 16; ++r) {
                        float ar = __shfl(alpha, (r & 3) + 8 * (r >> 2) + 4 * hh_);
#pragma unroll
                        for (int dt = 0; dt < 4; ++dt) acco[dt][r] *= ar;
                    }
                }

                // P = exp2(S' - m'), row sum, pack to bf16 pairs
                float psum = 0.f;
                uint32_t pkA[2][4], pkB[2][4];
#pragma unroll
                for (int kvt = 0; kvt < 2; ++kvt)
#pragma unroll
                    for (int sg = 0; sg < 4; ++sg) {
                        float p0 = __builtin_amdgcn_exp2f(sacc[kvt][4 * sg + 0] - mrow);
                        float p1 = __builtin_amdgcn_exp2f(sacc[kvt][4 * sg + 1] - mrow);
                        float p2 = __builtin_amdgcn_exp2f(sacc[kvt][4 * sg + 2] - mrow);
                        float p3 = __builtin_amdgcn_exp2f(sacc[kvt][4 * sg + 3] - mrow);
                        psum += (p0 + p1) + (p2 + p3);
                        pkA[kvt][sg] = pack_bf16(p0, p1);
                        pkB[kvt][sg] = pack_bf16(p2, p3);
                    }
                {
                    uint32_t pa_ = __builtin_bit_cast(uint32_t, psum), xx_, yy_;
                    SWAP32(xx_, yy_, pa_, pa_);
                    psum = __builtin_bit_cast(float, xx_) +
                           __builtin_bit_cast(float, yy_);
                }
                lrow += psum;

                // O += P V  (P A-frags assembled via cross-half swaps)
                __builtin_amdgcn_s_setprio(1);
#pragma unroll
                for (int w = 0; w < 4; ++w) {   // 16-kv slot within 64-kv half
                    const int kvt = w >> 1, kbl = w & 1;
                    uint32_t r0, r1, r2, r3;
                    SWAP32(r0, r2, pkA[kvt][2 * kbl], pkA[kvt][2 * kbl + 1]);
                    SWAP32(r1, r3, pkB[kvt][2 * kbl], pkB[kvt][2 * kbl + 1]);
                    union { uint32_t u[4]; bf16x8 v; } pa;
                    pa.u[0] = r0; pa.u[1] = r1; pa.u[2] = r2; pa.u[3] = r3;
#pragma unroll
                    for (int dt = 0; dt < 4; ++dt) {
                        int d = dt * 32 + l31;
                        int r = d >> 1;
                        int inner = ((d & 1) << 7) + w * 32 + hh_ * 16;
                        bf16x8 vf = *(const bf16x8*)(Vb + r * 256 + (inner ^ ((r & 15) << 4)));
                        acco[dt] = MFMA32(pa.v, vf, acco[dt]);
                    }
                }
                __builtin_amdgcn_s_setprio(0);
            }

            if (jt + 1 < nt) {
                asm volatile("s_waitcnt vmcnt(0)" ::: "memory");  // tile jt+1 landed
                __builtin_amdgcn_sched_barrier(0);
                __builtin_amdgcn_s_barrier();   // publish tile jt+1, release buf
                __builtin_amdgcn_sched_barrier(0);
            }
        }

        // ---- intra-block flash combine: merge kv halves (waves w, w+4) ----
        __syncthreads();                        // all waves done reading LDS
        float* ex = (float*)smem;               // 4 chunks x 4096 f32 (64 KB)
        float* ml = (float*)(smem + 65536);     // 4 chunks x 64 x {m,l} (2 KB)
        if (kvh == 1) {
            float* dst = ex + qc * 4096;
#pragma unroll
            for (int dt = 0; dt < 4; ++dt)
#pragma unroll
                for (int r = 0; r < 16; ++r)
                    dst[(dt * 16 + r) * 64 + lane] = acco[dt][r];
            ml[qc * 128 + lane * 2 + 0] = mrow;
            ml[qc * 128 + lane * 2 + 1] = lrow;
        }
        __syncthreads();
        if (kvh == 0) {
            float m1 = ml[qc * 128 + lane * 2 + 0];
            float l1 = ml[qc * 128 + lane * 2 + 1];
            float M  = fmaxf(mrow, m1);
            float av = __builtin_amdgcn_exp2f(mrow - M);
            float bv = __builtin_amdgcn_exp2f(m1 - M);  // 0 if half empty
            float lf = lrow * av + l1 * bv;
            float sA = av / lf, sB = bv / lf;
            const float* src = ex + qc * 4096;
            const int bb = bh >> 3, hd = bh & 7;
#pragma unroll
            for (int r = 0; r < 16; ++r) {
                int ql = (r & 3) + 8 * (r >> 2) + 4 * hh_;
                float sa = __shfl(sA, ql);
                float sb = __shfl(sB, ql);
                int t = qwave + ql;
                float* o = out + (size_t)(bb * 2048 + t) * 1024 + hd * 128 + l31;
#pragma unroll
                for (int dt = 0; dt < 4; ++dt)
                    o[dt * 32] = acco[dt][r] * sa + src[(dt * 16 + r) * 64 + lane] * sb;
            }
        }
        // drain combine stores before next strip's staging/waits
        asm volatile("s_waitcnt vmcnt(0)" ::: "memory");
    }
#undef STAGE128
}

// ---------------------------------------------------------------------------
extern "C" void kernel_launch(void* const* d_in, const int* in_sizes, int n_in,
                              void* d_out, int out_size, void* d_ws, size_t ws_size,
                              hipStream_t stream) {
    const float* x  = (const float*)d_in[0];
    const float* w  = (const float*)d_in[1];
    const float* bK = (const float*)d_in[2];
    const float* bQ = (const float*)d_in[3];
    const float* bV = (const float*)d_in[4];

    // workspace layout (bytes): xb 8,388,608 | W 3,145,728 (uses 2,359,296) |
    // qkv 50,331,648
    short* xb  = (short*)d_ws;
    short* W   = (short*)((char*)d_ws + 8388608);
    short* qkv = (short*)((char*)d_ws + 8388608 + 3145728);
    float* out = (float*)d_out;

    // allow 128 KB dynamic LDS (idempotent; not a stream op, capture-safe)
    hipFuncSetAttribute((const void*)attn_kernel,
                        hipFuncAttributeMaxDynamicSharedMemorySize, 131072);

    prep_kernel<<<2048, 256, 0, stream>>>(x, w, bK, bQ, bV, xb, W, qkv);
    proj_gemm<<<64 * 18, 256, 0, stream>>>(xb, W, qkv);
    attn_kernel<<<256, 512, 131072, stream>>>(qkv, out);
}

// Round 13
// 96.055 us; speedup vs baseline: 1.0455x; 1.0286x over previous
//
#include <hip/hip_runtime.h>
#include <hip/hip_bf16.h>
#include <stdint.h>

typedef __attribute__((ext_vector_type(8))) short bf16x8;
typedef __attribute__((ext_vector_type(4))) float f32x4;
typedef __attribute__((ext_vector_type(16))) float f32x16;

#define MFMA16(a,b,c) __builtin_amdgcn_mfma_f32_16x16x32_bf16((a),(b),(c),0,0,0)
#define MFMA32(a,b,c) __builtin_amdgcn_mfma_f32_32x32x16_bf16((a),(b),(c),0,0,0)
#define AS1 __attribute__((address_space(1)))
#define AS3 __attribute__((address_space(3)))

__device__ inline short f2bf(float f) {
    union { __hip_bfloat16 h; short s; } u;
    u.h = __float2bfloat16(f);
    return u.s;
}
__device__ inline uint32_t pack_bf16(float a, float b) {
    union { __hip_bfloat16 h; uint16_t u; } ua, ub;
    ua.h = __float2bfloat16(a); ub.h = __float2bfloat16(b);
    return (uint32_t)ua.u | ((uint32_t)ub.u << 16);
}

// cross-half register exchange
#if __has_builtin(__builtin_amdgcn_permlane32_swap)
#define SWAP32(x, y, a, b) { auto _r = __builtin_amdgcn_permlane32_swap((a),(b),false,false); \
                             (x) = _r[0]; (y) = _r[1]; }
#else
#define SWAP32(x, y, a, b) { uint32_t _ta = __shfl_xor((uint32_t)(a),32); \
                             uint32_t _tb = __shfl_xor((uint32_t)(b),32); \
                             (x) = hh_ ? _tb : (a); (y) = hh_ ? (b) : _ta; }
#endif

// S' = S * scale * log2(e): fold into Wq so attention exp is native exp2.
#define QSCALE 0.12751879523879295f   // (1/sqrt(128)) * log2(e)

// ---------------------------------------------------------------------------
// Kernel 1: eff-weight mix -> COMPACTED bf16 W [3][768][512]; x f32 -> bf16.
// R12 -> R13 changes: (1) W-section vectorized 8-wide (eff is uniform over
// any 8-aligned e-group since the e<256 boundary is 8-aligned): 2x float4
// loads + 1x uint4 store per projection instead of scalar f32/short ops.
// (2) the 12.6 MB qkv zero-fill MOVED to proj_gemm as extra blocks (it has
// no dependency on prep outputs; only attn needs it) -> overlaps with the
// compute-bound GEMM instead of serializing here.
// ---------------------------------------------------------------------------
#define NW (8*128*512)        // 524288 logical W elements per projection
#define NWC (768*512)         // 393216 compacted W elements per projection
#define NWG (768*64)          // 49152 8-wide W groups per projection
#define NX4 (8192*512/4)      // 1048576 float4 chunks of x
#define NZ1 262144            // uint4 chunks per zero region (K / Q / V)

__global__ void prep_kernel(const float* __restrict__ x,
                            const float* __restrict__ w,
                            const float* __restrict__ bK,
                            const float* __restrict__ bQ,
                            const float* __restrict__ bV,
                            short* __restrict__ xb,    // [8192][512]
                            short* __restrict__ W)     // [3][768][512] (K,Q,V)
{
    const float w0 = w[0], w1 = w[1], w2 = w[2], w3 = w[3];
    for (int i = blockIdx.x * blockDim.x + threadIdx.x; i < NX4 + NWG;
         i += gridDim.x * blockDim.x) {
        if (i < NX4) {
            float4 v = ((const float4*)x)[i];
            short4 o;
            o.x = f2bf(v.x); o.y = f2bf(v.y); o.z = f2bf(v.z); o.w = f2bf(v.w);
            ((short4*)xb)[i] = o;
        } else {
            int ii = i - NX4;                   // 0..NWG-1
            int r = ii >> 6, g = ii & 63;       // compacted row, e-group
            int e0 = g * 8;
            int h, d;
            if (r < 512) { h = r >> 7;            d = r & 127; }
            else         { int rr = r - 512; h = 4 + (rr >> 6); d = rr & 63; }
            float eff = 0.f;
            bool elo = (e0 < 256);
            if (h < 4) { eff += w2; if (d < 64 && elo) eff += w0; }
            if (d < 32 && elo) eff += w1;
            if (d < 64) eff += w3;
            size_t src = ((size_t)h << 16) + ((size_t)d << 9) + e0;
            int dst = r * 512 + e0;
            {
                float4 a0 = *(const float4*)(bK + src);
                float4 a1 = *(const float4*)(bK + src + 4);
                uint4 o;
                o.x = pack_bf16(eff * a0.x, eff * a0.y);
                o.y = pack_bf16(eff * a0.z, eff * a0.w);
                o.z = pack_bf16(eff * a1.x, eff * a1.y);
                o.w = pack_bf16(eff * a1.z, eff * a1.w);
                *(uint4*)(W + dst) = o;
            }
            {
                float eq = eff * QSCALE;
                float4 a0 = *(const float4*)(bQ + src);
                float4 a1 = *(const float4*)(bQ + src + 4);
                uint4 o;
                o.x = pack_bf16(eq * a0.x, eq * a0.y);
                o.y = pack_bf16(eq * a0.z, eq * a0.w);
                o.z = pack_bf16(eq * a1.x, eq * a1.y);
                o.w = pack_bf16(eq * a1.z, eq * a1.w);
                *(uint4*)(W + NWC + dst) = o;
            }
            {
                float4 a0 = *(const float4*)(bV + src);
                float4 a1 = *(const float4*)(bV + src + 4);
                uint4 o;
                o.x = pack_bf16(eff * a0.x, eff * a0.y);
                o.y = pack_bf16(eff * a0.z, eff * a0.w);
                o.z = pack_bf16(eff * a1.x, eff * a1.y);
                o.w = pack_bf16(eff * a1.z, eff * a1.w);
                *(uint4*)(W + 2 * NWC + dst) = o;
            }
        }
    }
}

// ---------------------------------------------------------------------------
// Kernel 2: C[8192,2304] = xb[8192,512] @ W[2304,512]^T   (compacted W)
// 18 column-tiles (6/proj): u<4 = head u full; u=4 -> heads 4,5 (d<64);
// u=5 -> heads 6,7 (d<64).  Bijective XCD grid swizzle (1152=8*144).
// Blocks 1152..1215 (64 extra) do the structurally-zero qkv region fill
// (heads 4-7, d>=64; bit-identical +0.0 to what the full GEMM computed),
// overlapping with the compute-bound GEMM blocks.  Write sets disjoint:
// GEMM writes heads 4-7 only at d<64.
// ---------------------------------------------------------------------------
__global__ __launch_bounds__(256)
void proj_gemm(const short* __restrict__ A,    // [8192][512]
               const short* __restrict__ Bw,   // [2304][512]
               short* __restrict__ qkv)
{
    __shared__ short S[128 * 128];             // 32 KB: staging + repack
    const int tid = threadIdx.x;
    const size_t HSTRIDE = (size_t)2048 * 128;

    if (blockIdx.x >= 1152) {
        // ---- zero-fill blocks (R12-prep mapping, verified) ----------------
        const uint4 zz = {0u, 0u, 0u, 0u};
        int zb = blockIdx.x - 1152;             // 0..63
        for (int z = zb * 256 + tid; z < 3 * NZ1; z += 64 * 256) {
            int reg = z / NZ1;                  // 0=K, 1=Q, 2=V
            int zz_ = z - reg * NZ1;            // 0..262143
            int bhidx = zz_ >> 14;              // 16 zero heads
            int rem = zz_ & 16383;
            int bh = (bhidx >> 2) * 8 + 4 + (bhidx & 3);
            short* p;
            if (reg < 2) {
                // K/Q [t][d]: zero d 64..127 of every t row
                int t = rem >> 3, ch = rem & 7;
                p = qkv + (size_t)reg * 32 * HSTRIDE + (size_t)bh * HSTRIDE
                    + (size_t)t * 128 + 64 + ch * 8;
            } else {
                // V [d][t]: rows d 64..127 contiguous
                p = qkv + (size_t)64 * HSTRIDE + (size_t)bh * HSTRIDE
                    + (size_t)64 * 2048 + (size_t)rem * 8;
            }
            *(uint4*)p = zz;
        }
        return;
    }

    short* As = S;                             // 16 KB
    short* Bs = S + 128 * 64;                  // 16 KB
    const int lane = tid & 63;
    const int wave = tid >> 6;
    const int wr = wave >> 1, wc = wave & 1;
    const int l15 = lane & 15, lk = lane >> 4;

    // bijective XCD swizzle: 1152 blocks, 144 consecutive per XCD
    const int wg = (blockIdx.x & 7) * 144 + (blockIdx.x >> 3);
    const int bm = (wg / 18) * 128;
    const int tt = wg % 18;                    // global column tile 0..17
    const int bn = tt * 128;
    const int p = tt / 6;                      // projection 0=K,1=Q,2=V
    const int u = tt % 6;                      // within-proj tile

    char* Ab = (char*)As;
    char* Bb = (char*)Bs;
    char* Sb = (char*)S;
    f32x4 acc[4][4] = {};

    for (int k0 = 0; k0 < 512; k0 += 64) {
        __syncthreads();
#pragma unroll
        for (int i = 0; i < 4; ++i) {
            int c = i * 256 + tid;              // 0..1023, 16B chunk
            int lin = c * 16;                   // linear byte in 16 KB tile
            int row = lin >> 7;                 // 0..127
            int cof = ((lin & 127) ^ ((row & 7) << 4)) >> 1;   // shorts
            __builtin_amdgcn_global_load_lds(
                (const AS1 void*)(A + (size_t)(bm + row) * 512 + k0 + cof),
                (AS3 void*)(As + c * 8), 16, 0, 0);
            __builtin_amdgcn_global_load_lds(
                (const AS1 void*)(Bw + (size_t)(bn + row) * 512 + k0 + cof),
                (AS3 void*)(Bs + c * 8), 16, 0, 0);
        }
        __syncthreads();                        // drains vmcnt(0) (m97 pattern)
#pragma unroll
        for (int kk = 0; kk < 2; ++kk) {
            bf16x8 af[4], bfv[4];
#pragma unroll
            for (int mi = 0; mi < 4; ++mi) {
                int row = wr * 64 + mi * 16 + l15;
                af[mi] = *(const bf16x8*)(Ab + ((row * 128 + kk * 64 + lk * 16) ^ ((row & 7) << 4)));
            }
#pragma unroll
            for (int ni = 0; ni < 4; ++ni) {
                int row = wc * 64 + ni * 16 + l15;
                bfv[ni] = *(const bf16x8*)(Bb + ((row * 128 + kk * 64 + lk * 16) ^ ((row & 7) << 4)));
            }
#pragma unroll
            for (int mi = 0; mi < 4; ++mi)
#pragma unroll
                for (int ni = 0; ni < 4; ++ni)
                    acc[mi][ni] = MFMA16(af[mi], bfv[ni], acc[mi][ni]);
        }
    }

    // ---- epilogue: repack C-tile via LDS, store coalesced -----------------
    const int b = bm >> 11;
    const int tbase = bm & 2047;

    __syncthreads();                            // staging reads done
    if (p == 2) {
        // V: LDS T[dl][tl] (transpose), pack r-pairs (consecutive tl)
#pragma unroll
        for (int mi = 0; mi < 4; ++mi) {
#pragma unroll
            for (int ni = 0; ni < 4; ++ni) {
                int dl = wc * 64 + ni * 16 + l15;
                int tlb = wr * 64 + mi * 16 + lk * 4;
                int byte0 = (dl * 256 + tlb * 2) ^ ((dl & 7) << 4);
                *(uint32_t*)(Sb + byte0)     = pack_bf16(acc[mi][ni][0], acc[mi][ni][1]);
                *(uint32_t*)(Sb + byte0 + 4) = pack_bf16(acc[mi][ni][2], acc[mi][ni][3]);
            }
        }
    } else {
        // K/Q: LDS T[tl][dl]
#pragma unroll
        for (int mi = 0; mi < 4; ++mi) {
#pragma unroll
            for (int ni = 0; ni < 4; ++ni) {
                int dl = wc * 64 + ni * 16 + l15;
#pragma unroll
                for (int r = 0; r < 4; ++r) {
                    int tl = wr * 64 + mi * 16 + lk * 4 + r;
                    *(short*)(Sb + ((tl * 256 + dl * 2) ^ ((tl & 7) << 4))) = f2bf(acc[mi][ni][r]);
                }
            }
        }
    }
    __syncthreads();

#pragma unroll
    for (int i = 0; i < 8; ++i) {
        int c = i * 256 + tid;                  // 0..2047 16B chunks
        int row = c >> 4;
        uint4 v = *(const uint4*)(Sb + row * 256 + (((c & 15) * 16) ^ ((row & 7) << 4)));
        if (p == 2) {
            // row = d-index in tile, cols = t
            int head, drow;
            if (u < 4) { head = u;                         drow = row;      }
            else       { head = 4 + (u - 4) * 2 + (row >> 6); drow = row & 63; }
            short* dst = qkv + (size_t)2 * (32 * 2048 * 128)
                       + (size_t)(b * 8 + head) * 128 * 2048;
            *(uint4*)(dst + (size_t)drow * 2048 + tbase + (c & 15) * 8) = v;
        } else {
            // row = t, cols = d-index in tile
            int cc = c & 15;
            int head, dcol;
            if (u < 4) { head = u;                          dcol = cc * 8;       }
            else       { head = 4 + (u - 4) * 2 + (cc >> 3); dcol = (cc & 7) * 8; }
            short* dst = qkv + (size_t)p * (32 * 2048 * 128)
                       + (size_t)(b * 8 + head) * 2048 * 128;
            *(uint4*)(dst + (size_t)(tbase + row) * 128 + dcol) = v;
        }
    }
}

// ---------------------------------------------------------------------------
// Kernel 3: causal flash attention — R12 version VERBATIM (verified 58.6 us,
// best measured).  KVBLK=128 dbuf, hoisted staging offsets, 256 blocks x 512
// thr, strips a & 15-a (uniform 17 iters), bh%8=XCD, cross-half reductions
// via permlane32_swap (pure VALU), per-strip LDS flash combine.
// Dynamic LDS 131072 B: 2 buffers x {K 32K | V 2x16K}. 1 block/CU.
// ---------------------------------------------------------------------------
__global__ __launch_bounds__(512, 2)
void attn_kernel(const short* __restrict__ qkv, float* __restrict__ out)
{
    extern __shared__ char smem[];
    const int tid = threadIdx.x, lane = tid & 63, wave = tid >> 6;
    const int l31 = lane & 31;
    const int hh_ = lane >> 5;

    const int bh = blockIdx.x & 31;             // bh%8 = XCD under round-robin
    const int a = blockIdx.x >> 5;              // 0..7

    const int qc = wave & 3;                    // q sub-block (32 rows)
    const int kvh = wave >> 2;                  // kv half of staged 128-kv tile

    const size_t HSTRIDE = (size_t)2048 * 128;
    const short* Kp = qkv + (size_t)bh * HSTRIDE;                    // [t][d]
    const short* Qp = qkv + (size_t)32 * HSTRIDE + (size_t)bh * HSTRIDE;
    const short* Vp = qkv + (size_t)64 * HSTRIDE + (size_t)bh * HSTRIDE; // [d][t]

    // ---- hoisted staging offsets (tid-only; computed once) ----------------
    int koffs[4], voffs[4];
#pragma unroll
    for (int i = 0; i < 4; ++i) {
        int c = i * 512 + tid;                  // 0..2047, 16B chunk index
        int rk = c >> 4;                        // K row 0..127
        int kof = (((c * 16) & 255) ^ ((rk & 15) << 4)) >> 1;
        koffs[i] = rk * 128 + kof;              // + j0*128 at stage time
        int sub = c >> 10, cc = c & 1023;       // V subtile, chunk within
        int rv = cc >> 4;                       // pair-row 0..63
        int pp = ((cc * 16) & 255) ^ ((rv & 15) << 4);
        int d = 2 * rv + (pp >> 7);
        int t = (pp & 127) >> 1;
        voffs[i] = d * 2048 + sub * 64 + t;     // + j0 at stage time
    }

#define STAGE128(J0, BUF) {                                                   \
        char* _b = smem + ((BUF) << 16);                                      \
        _Pragma("unroll")                                                     \
        for (int i_ = 0; i_ < 4; ++i_) {                                      \
            int c = i_ * 512 + tid;                                           \
            __builtin_amdgcn_global_load_lds(                                 \
                (const AS1 void*)(Kp + koffs[i_] + (J0) * 128),               \
                (AS3 void*)(_b + c * 16), 16, 0, 0);                          \
            __builtin_amdgcn_global_load_lds(                                 \
                (const AS1 void*)(Vp + voffs[i_] + (J0)),                     \
                (AS3 void*)(_b + 32768 + c * 16), 16, 0, 0);                  \
        }                                                                     \
    }

    for (int sidx = 0; sidx < 2; ++sidx) {
        const int sp = sidx ? (15 - a) : a;     // strip index 0..15
        const int q0 = sp * 128;
        const int nt = sp + 1;                  // 128-kv tiles
        const int qwave = q0 + qc * 32;
        const int qglob = qwave + l31;

        __syncthreads();                        // LDS free (prev combine done)

        // Q B-operand frags
        bf16x8 qf[8];
        {
            const short* qrow = Qp + (size_t)(q0 + qc * 32 + l31) * 128 + hh_ * 8;
#pragma unroll
            for (int dblk = 0; dblk < 8; ++dblk)
                qf[dblk] = *(const bf16x8*)(qrow + dblk * 16);
        }

        float mrow = -1e30f, lrow = 0.f;
        f32x16 acco[4] = {};                    // O[q(reg)][dt*32 + l31]

        STAGE128(0, 0);                         // prologue: tile 0 -> buf 0
        asm volatile("s_waitcnt vmcnt(0)" ::: "memory");
        __builtin_amdgcn_sched_barrier(0);
        __builtin_amdgcn_s_barrier();           // tile 0 visible to all waves
        __builtin_amdgcn_sched_barrier(0);

        for (int jt = 0; jt < nt; ++jt) {
            const int j0 = jt << 7;
            if (jt + 1 < nt)
                STAGE128((jt + 1) << 7, (jt + 1) & 1);

            const int kv0 = j0 + kvh * 64;      // this wave's 64-kv window
            if (kv0 <= qwave + 31) {            // wave-uniform causal gate
                const char* Kb = smem + ((jt & 1) << 16);
                const char* Vb = Kb + 32768 + (kvh << 14);   // sub = kvh

                // S'^T = K Q'^T : lane pair (l, l^32) holds S'[kv][q=l31]
                f32x16 sacc[2] = {};
                __builtin_amdgcn_s_setprio(1);
#pragma unroll
                for (int dblk = 0; dblk < 8; ++dblk) {
#pragma unroll
                    for (int kvt = 0; kvt < 2; ++kvt) {
                        int krow = kvh * 64 + kvt * 32 + l31;
                        bf16x8 kf = *(const bf16x8*)(Kb + krow * 256 +
                            ((dblk * 32 + hh_ * 16) ^ ((krow & 15) << 4)));
                        sacc[kvt] = MFMA32(kf, qf[dblk], sacc[kvt]);
                    }
                }
                __builtin_amdgcn_s_setprio(0);

                // causal mask: only the straddle tile
                if (kv0 + 63 > qwave) {
#pragma unroll
                    for (int kvt = 0; kvt < 2; ++kvt)
#pragma unroll
                        for (int r = 0; r < 16; ++r) {
                            int kvglob = kv0 + kvt * 32 + (r & 3) + 8 * (r >> 2) + 4 * hh_;
                            if (kvglob > qglob) sacc[kvt][r] = -1e30f;
                        }
                }

                // row max: in-lane tree + cross-half permlane (pure VALU)
                float pmax = -1e30f;
#pragma unroll
                for (int kvt = 0; kvt < 2; ++kvt)
#pragma unroll
                    for (int r = 0; r < 16; r += 4) {
                        float a2 = fmaxf(sacc[kvt][r], sacc[kvt][r + 1]);
                        float b2 = fmaxf(sacc[kvt][r + 2], sacc[kvt][r + 3]);
                        pmax = fmaxf(pmax, fmaxf(a2, b2));
                    }
                {
                    uint32_t pa_ = __builtin_bit_cast(uint32_t, pmax), xx_, yy_;
                    SWAP32(xx_, yy_, pa_, pa_);
                    pmax = fmaxf(__builtin_bit_cast(float, xx_),
                                 __builtin_bit_cast(float, yy_));
                }

                // defer-max: rescale only when max grew by > 8 nats
                if (!__all(pmax - mrow <= 11.5416f)) {
                    float mn = fmaxf(mrow, pmax);
                    float alpha = __builtin_amdgcn_exp2f(mrow - mn);
                    mrow = mn;
                    lrow *= alpha;
#pragma unroll
                    for (int r = 0; r < 16; ++r) {
                        float ar = __shfl(alpha, (r & 3) + 8 * (r >> 2) + 4 * hh_);
#pragma unroll
                        for (int dt = 0; dt < 4; ++dt) acco[dt][r] *= ar;
                    }
                }

                // P = exp2(S' - m'), row sum, pack to bf16 pairs
                float psum = 0.f;
                uint32_t pkA[2][4], pkB[2][4];
#pragma unroll
                for (int kvt = 0; kvt < 2; ++kvt)
#pragma unroll
                    for (int sg = 0; sg < 4; ++sg) {
                        float p0 = __builtin_amdgcn_exp2f(sacc[kvt][4 * sg + 0] - mrow);
                        float p1 = __builtin_amdgcn_exp2f(sacc[kvt][4 * sg + 1] - mrow);
                        float p2 = __builtin_amdgcn_exp2f(sacc[kvt][4 * sg + 2] - mrow);
                        float p3 = __builtin_amdgcn_exp2f(sacc[kvt][4 * sg + 3] - mrow);
                        psum += (p0 + p1) + (p2 + p3);
                        pkA[kvt][sg] = pack_bf16(p0, p1);
                        pkB[kvt][sg] = pack_bf16(p2, p3);
                    }
                {
                    uint32_t pa_ = __builtin_bit_cast(uint32_t, psum), xx_, yy_;
                    SWAP32(xx_, yy_, pa_, pa_);
                    psum = __builtin_bit_cast(float, xx_) +
                           __builtin_bit_cast(float, yy_);
                }
                lrow += psum;

                // O += P V  (P A-frags assembled via cross-half swaps)
                __builtin_amdgcn_s_setprio(1);
#pragma unroll
                for (int w = 0; w < 4; ++w) {   // 16-kv slot within 64-kv half
                    const int kvt = w >> 1, kbl = w & 1;
                    uint32_t r0, r1, r2, r3;
                    SWAP32(r0, r2, pkA[kvt][2 * kbl], pkA[kvt][2 * kbl + 1]);
                    SWAP32(r1, r3, pkB[kvt][2 * kbl], pkB[kvt][2 * kbl + 1]);
                    union { uint32_t u[4]; bf16x8 v; } pa;
                    pa.u[0] = r0; pa.u[1] = r1; pa.u[2] = r2; pa.u[3] = r3;
#pragma unroll
                    for (int dt = 0; dt < 4; ++dt) {
                        int d = dt * 32 + l31;
                        int r = d >> 1;
                        int inner = ((d & 1) << 7) + w * 32 + hh_ * 16;
                        bf16x8 vf = *(const bf16x8*)(Vb + r * 256 + (inner ^ ((r & 15) << 4)));
                        acco[dt] = MFMA32(pa.v, vf, acco[dt]);
                    }
                }
                __builtin_amdgcn_s_setprio(0);
            }

            if (jt + 1 < nt) {
                asm volatile("s_waitcnt vmcnt(0)" ::: "memory");  // tile jt+1 landed
                __builtin_amdgcn_sched_barrier(0);
                __builtin_amdgcn_s_barrier();   // publish tile jt+1, release buf
                __builtin_amdgcn_sched_barrier(0);
            }
        }

        // ---- intra-block flash combine: merge kv halves (waves w, w+4) ----
        __syncthreads();                        // all waves done reading LDS
        float* ex = (float*)smem;               // 4 chunks x 4096 f32 (64 KB)
        float* ml = (float*)(smem + 65536);     // 4 chunks x 64 x {m,l} (2 KB)
        if (kvh == 1) {
            float* dst = ex + qc * 4096;
#pragma unroll
            for (int dt = 0; dt < 4; ++dt)
#pragma unroll
                for (int r = 0; r < 16; ++r)
                    dst[(dt * 16 + r) * 64 + lane] = acco[dt][r];
            ml[qc * 128 + lane * 2 + 0] = mrow;
            ml[qc * 128 + lane * 2 + 1] = lrow;
        }
        __syncthreads();
        if (kvh == 0) {
            float m1 = ml[qc * 128 + lane * 2 + 0];
            float l1 = ml[qc * 128 + lane * 2 + 1];
            float M  = fmaxf(mrow, m1);
            float av = __builtin_amdgcn_exp2f(mrow - M);
            float bv = __builtin_amdgcn_exp2f(m1 - M);  // 0 if half empty
            float lf = lrow * av + l1 * bv;
            float sA = av / lf, sB = bv / lf;
            const float* src = ex + qc * 4096;
            const int bb = bh >> 3, hd = bh & 7;
#pragma unroll
            for (int r = 0; r < 16; ++r) {
                int ql = (r & 3) + 8 * (r >> 2) + 4 * hh_;
                float sa = __shfl(sA, ql);
                float sb = __shfl(sB, ql);
                int t = qwave + ql;
                float* o = out + (size_t)(bb * 2048 + t) * 1024 + hd * 128 + l31;
#pragma unroll
                for (int dt = 0; dt < 4; ++dt)
                    o[dt * 32] = acco[dt][r] * sa + src[(dt * 16 + r) * 64 + lane] * sb;
            }
        }
        // drain combine stores before next strip's staging/waits
        asm volatile("s_waitcnt vmcnt(0)" ::: "memory");
    }
#undef STAGE128
}

// ---------------------------------------------------------------------------
extern "C" void kernel_launch(void* const* d_in, const int* in_sizes, int n_in,
                              void* d_out, int out_size, void* d_ws, size_t ws_size,
                              hipStream_t stream) {
    const float* x  = (const float*)d_in[0];
    const float* w  = (const float*)d_in[1];
    const float* bK = (const float*)d_in[2];
    const float* bQ = (const float*)d_in[3];
    const float* bV = (const float*)d_in[4];

    // workspace layout (bytes): xb 8,388,608 | W 3,145,728 (uses 2,359,296) |
    // qkv 50,331,648
    short* xb  = (short*)d_ws;
    short* W   = (short*)((char*)d_ws + 8388608);
    short* qkv = (short*)((char*)d_ws + 8388608 + 3145728);
    float* out = (float*)d_out;

    // allow 128 KB dynamic LDS (idempotent; not a stream op, capture-safe)
    hipFuncSetAttribute((const void*)attn_kernel,
                        hipFuncAttributeMaxDynamicSharedMemorySize, 131072);

    prep_kernel<<<2048, 256, 0, stream>>>(x, w, bK, bQ, bV, xb, W);
    proj_gemm<<<1216, 256, 0, stream>>>(xb, W, qkv);
    attn_kernel<<<256, 512, 131072, stream>>>(qkv, out);
}

// Round 14
// 94.254 us; speedup vs baseline: 1.0655x; 1.0191x over previous
//
#include <hip/hip_runtime.h>
#include <hip/hip_bf16.h>
#include <stdint.h>

typedef __attribute__((ext_vector_type(8))) short bf16x8;
typedef __attribute__((ext_vector_type(4))) float f32x4;
typedef __attribute__((ext_vector_type(16))) float f32x16;

#define MFMA16(a,b,c) __builtin_amdgcn_mfma_f32_16x16x32_bf16((a),(b),(c),0,0,0)
#define MFMA32(a,b,c) __builtin_amdgcn_mfma_f32_32x32x16_bf16((a),(b),(c),0,0,0)
#define AS1 __attribute__((address_space(1)))
#define AS3 __attribute__((address_space(3)))

__device__ inline short f2bf(float f) {
    union { __hip_bfloat16 h; short s; } u;
    u.h = __float2bfloat16(f);
    return u.s;
}
__device__ inline uint32_t pack_bf16(float a, float b) {
    union { __hip_bfloat16 h; uint16_t u; } ua, ub;
    ua.h = __float2bfloat16(a); ub.h = __float2bfloat16(b);
    return (uint32_t)ua.u | ((uint32_t)ub.u << 16);
}

// cross-half register exchange
#if __has_builtin(__builtin_amdgcn_permlane32_swap)
#define SWAP32(x, y, a, b) { auto _r = __builtin_amdgcn_permlane32_swap((a),(b),false,false); \
                             (x) = _r[0]; (y) = _r[1]; }
#else
#define SWAP32(x, y, a, b) { uint32_t _ta = __shfl_xor((uint32_t)(a),32); \
                             uint32_t _tb = __shfl_xor((uint32_t)(b),32); \
                             (x) = hh_ ? _tb : (a); (y) = hh_ ? (b) : _ta; }
#endif

// S' = S * scale * log2(e): fold into Wq so attention exp is native exp2.
#define QSCALE 0.12751879523879295f   // (1/sqrt(128)) * log2(e)

// ---------------------------------------------------------------------------
// Kernel 1: eff-weight mix -> COMPACTED bf16 W [3][768][512]; x f32 -> bf16.
// (R13-verified: 8-wide vectorized W section; zero-fill lives in proj_gemm.)
// ---------------------------------------------------------------------------
#define NW (8*128*512)        // 524288 logical W elements per projection
#define NWC (768*512)         // 393216 compacted W elements per projection
#define NWG (768*64)          // 49152 8-wide W groups per projection
#define NX4 (8192*512/4)      // 1048576 float4 chunks of x
#define NZ1 262144            // uint4 chunks per zero region (K / Q / V)

__global__ void prep_kernel(const float* __restrict__ x,
                            const float* __restrict__ w,
                            const float* __restrict__ bK,
                            const float* __restrict__ bQ,
                            const float* __restrict__ bV,
                            short* __restrict__ xb,    // [8192][512]
                            short* __restrict__ W)     // [3][768][512] (K,Q,V)
{
    const float w0 = w[0], w1 = w[1], w2 = w[2], w3 = w[3];
    for (int i = blockIdx.x * blockDim.x + threadIdx.x; i < NX4 + NWG;
         i += gridDim.x * blockDim.x) {
        if (i < NX4) {
            float4 v = ((const float4*)x)[i];
            short4 o;
            o.x = f2bf(v.x); o.y = f2bf(v.y); o.z = f2bf(v.z); o.w = f2bf(v.w);
            ((short4*)xb)[i] = o;
        } else {
            int ii = i - NX4;                   // 0..NWG-1
            int r = ii >> 6, g = ii & 63;       // compacted row, e-group
            int e0 = g * 8;
            int h, d;
            if (r < 512) { h = r >> 7;            d = r & 127; }
            else         { int rr = r - 512; h = 4 + (rr >> 6); d = rr & 63; }
            float eff = 0.f;
            bool elo = (e0 < 256);
            if (h < 4) { eff += w2; if (d < 64 && elo) eff += w0; }
            if (d < 32 && elo) eff += w1;
            if (d < 64) eff += w3;
            size_t src = ((size_t)h << 16) + ((size_t)d << 9) + e0;
            int dst = r * 512 + e0;
            {
                float4 a0 = *(const float4*)(bK + src);
                float4 a1 = *(const float4*)(bK + src + 4);
                uint4 o;
                o.x = pack_bf16(eff * a0.x, eff * a0.y);
                o.y = pack_bf16(eff * a0.z, eff * a0.w);
                o.z = pack_bf16(eff * a1.x, eff * a1.y);
                o.w = pack_bf16(eff * a1.z, eff * a1.w);
                *(uint4*)(W + dst) = o;
            }
            {
                float eq = eff * QSCALE;
                float4 a0 = *(const float4*)(bQ + src);
                float4 a1 = *(const float4*)(bQ + src + 4);
                uint4 o;
                o.x = pack_bf16(eq * a0.x, eq * a0.y);
                o.y = pack_bf16(eq * a0.z, eq * a0.w);
                o.z = pack_bf16(eq * a1.x, eq * a1.y);
                o.w = pack_bf16(eq * a1.z, eq * a1.w);
                *(uint4*)(W + NWC + dst) = o;
            }
            {
                float4 a0 = *(const float4*)(bV + src);
                float4 a1 = *(const float4*)(bV + src + 4);
                uint4 o;
                o.x = pack_bf16(eff * a0.x, eff * a0.y);
                o.y = pack_bf16(eff * a0.z, eff * a0.w);
                o.z = pack_bf16(eff * a1.x, eff * a1.y);
                o.w = pack_bf16(eff * a1.z, eff * a1.w);
                *(uint4*)(W + 2 * NWC + dst) = o;
            }
        }
    }
}

// ---------------------------------------------------------------------------
// Kernel 2: C[8192,2304] = xb[8192,512] @ W[2304,512]^T   (compacted W)
// R13 -> R14: (1) __launch_bounds__(256,4) caps VGPR at 128 -> 4 waves/SIMD
// possible (2-phase structure is barrier-stall-bound; wave overlap pays).
// (2) staging address math hoisted out of the K-loop (tid-only offsets,
// loop adds k0).  Everything else byte-identical to R13 (verified).
// Blocks 1152..1215 do the structurally-zero qkv region fill (overlapped).
// ---------------------------------------------------------------------------
__global__ __launch_bounds__(256, 4)
void proj_gemm(const short* __restrict__ A,    // [8192][512]
               const short* __restrict__ Bw,   // [2304][512]
               short* __restrict__ qkv)
{
    __shared__ short S[128 * 128];             // 32 KB: staging + repack
    const int tid = threadIdx.x;
    const size_t HSTRIDE = (size_t)2048 * 128;

    if (blockIdx.x >= 1152) {
        // ---- zero-fill blocks (R12-prep mapping, verified) ----------------
        const uint4 zz = {0u, 0u, 0u, 0u};
        int zb = blockIdx.x - 1152;             // 0..63
        for (int z = zb * 256 + tid; z < 3 * NZ1; z += 64 * 256) {
            int reg = z / NZ1;                  // 0=K, 1=Q, 2=V
            int zz_ = z - reg * NZ1;            // 0..262143
            int bhidx = zz_ >> 14;              // 16 zero heads
            int rem = zz_ & 16383;
            int bh = (bhidx >> 2) * 8 + 4 + (bhidx & 3);
            short* p;
            if (reg < 2) {
                // K/Q [t][d]: zero d 64..127 of every t row
                int t = rem >> 3, ch = rem & 7;
                p = qkv + (size_t)reg * 32 * HSTRIDE + (size_t)bh * HSTRIDE
                    + (size_t)t * 128 + 64 + ch * 8;
            } else {
                // V [d][t]: rows d 64..127 contiguous
                p = qkv + (size_t)64 * HSTRIDE + (size_t)bh * HSTRIDE
                    + (size_t)64 * 2048 + (size_t)rem * 8;
            }
            *(uint4*)p = zz;
        }
        return;
    }

    short* As = S;                             // 16 KB
    short* Bs = S + 128 * 64;                  // 16 KB
    const int lane = tid & 63;
    const int wave = tid >> 6;
    const int wr = wave >> 1, wc = wave & 1;
    const int l15 = lane & 15, lk = lane >> 4;

    // bijective XCD swizzle: 1152 blocks, 144 consecutive per XCD
    const int wg = (blockIdx.x & 7) * 144 + (blockIdx.x >> 3);
    const int bm = (wg / 18) * 128;
    const int tt = wg % 18;                    // global column tile 0..17
    const int bn = tt * 128;
    const int p = tt / 6;                      // projection 0=K,1=Q,2=V
    const int u = tt % 6;                      // within-proj tile

    char* Ab = (char*)As;
    char* Bb = (char*)Bs;
    char* Sb = (char*)S;
    f32x4 acc[4][4] = {};

    // hoisted staging offsets (tid-only)
    const short* baseA = A + (size_t)bm * 512;
    const short* baseB = Bw + (size_t)bn * 512;
    int soff[4], ldst[4];
#pragma unroll
    for (int i = 0; i < 4; ++i) {
        int c = i * 256 + tid;                  // 0..1023, 16B chunk
        int lin = c * 16;                       // linear byte in 16 KB tile
        int row = lin >> 7;                     // 0..127
        int cof = ((lin & 127) ^ ((row & 7) << 4)) >> 1;   // shorts
        soff[i] = row * 512 + cof;              // + k0 at stage time
        ldst[i] = c * 8;                        // LDS short offset
    }

    for (int k0 = 0; k0 < 512; k0 += 64) {
        __syncthreads();
#pragma unroll
        for (int i = 0; i < 4; ++i) {
            __builtin_amdgcn_global_load_lds(
                (const AS1 void*)(baseA + soff[i] + k0),
                (AS3 void*)(As + ldst[i]), 16, 0, 0);
            __builtin_amdgcn_global_load_lds(
                (const AS1 void*)(baseB + soff[i] + k0),
                (AS3 void*)(Bs + ldst[i]), 16, 0, 0);
        }
        __syncthreads();                        // drains vmcnt(0) (m97 pattern)
#pragma unroll
        for (int kk = 0; kk < 2; ++kk) {
            bf16x8 af[4], bfv[4];
#pragma unroll
            for (int mi = 0; mi < 4; ++mi) {
                int row = wr * 64 + mi * 16 + l15;
                af[mi] = *(const bf16x8*)(Ab + ((row * 128 + kk * 64 + lk * 16) ^ ((row & 7) << 4)));
            }
#pragma unroll
            for (int ni = 0; ni < 4; ++ni) {
                int row = wc * 64 + ni * 16 + l15;
                bfv[ni] = *(const bf16x8*)(Bb + ((row * 128 + kk * 64 + lk * 16) ^ ((row & 7) << 4)));
            }
#pragma unroll
            for (int mi = 0; mi < 4; ++mi)
#pragma unroll
                for (int ni = 0; ni < 4; ++ni)
                    acc[mi][ni] = MFMA16(af[mi], bfv[ni], acc[mi][ni]);
        }
    }

    // ---- epilogue: repack C-tile via LDS, store coalesced -----------------
    const int b = bm >> 11;
    const int tbase = bm & 2047;

    __syncthreads();                            // staging reads done
    if (p == 2) {
        // V: LDS T[dl][tl] (transpose), pack r-pairs (consecutive tl)
#pragma unroll
        for (int mi = 0; mi < 4; ++mi) {
#pragma unroll
            for (int ni = 0; ni < 4; ++ni) {
                int dl = wc * 64 + ni * 16 + l15;
                int tlb = wr * 64 + mi * 16 + lk * 4;
                int byte0 = (dl * 256 + tlb * 2) ^ ((dl & 7) << 4);
                *(uint32_t*)(Sb + byte0)     = pack_bf16(acc[mi][ni][0], acc[mi][ni][1]);
                *(uint32_t*)(Sb + byte0 + 4) = pack_bf16(acc[mi][ni][2], acc[mi][ni][3]);
            }
        }
    } else {
        // K/Q: LDS T[tl][dl]
#pragma unroll
        for (int mi = 0; mi < 4; ++mi) {
#pragma unroll
            for (int ni = 0; ni < 4; ++ni) {
                int dl = wc * 64 + ni * 16 + l15;
#pragma unroll
                for (int r = 0; r < 4; ++r) {
                    int tl = wr * 64 + mi * 16 + lk * 4 + r;
                    *(short*)(Sb + ((tl * 256 + dl * 2) ^ ((tl & 7) << 4))) = f2bf(acc[mi][ni][r]);
                }
            }
        }
    }
    __syncthreads();

#pragma unroll
    for (int i = 0; i < 8; ++i) {
        int c = i * 256 + tid;                  // 0..2047 16B chunks
        int row = c >> 4;
        uint4 v = *(const uint4*)(Sb + row * 256 + (((c & 15) * 16) ^ ((row & 7) << 4)));
        if (p == 2) {
            // row = d-index in tile, cols = t
            int head, drow;
            if (u < 4) { head = u;                         drow = row;      }
            else       { head = 4 + (u - 4) * 2 + (row >> 6); drow = row & 63; }
            short* dst = qkv + (size_t)2 * (32 * 2048 * 128)
                       + (size_t)(b * 8 + head) * 128 * 2048;
            *(uint4*)(dst + (size_t)drow * 2048 + tbase + (c & 15) * 8) = v;
        } else {
            // row = t, cols = d-index in tile
            int cc = c & 15;
            int head, dcol;
            if (u < 4) { head = u;                          dcol = cc * 8;       }
            else       { head = 4 + (u - 4) * 2 + (cc >> 3); dcol = (cc & 7) * 8; }
            short* dst = qkv + (size_t)p * (32 * 2048 * 128)
                       + (size_t)(b * 8 + head) * 2048 * 128;
            *(uint4*)(dst + (size_t)(tbase + row) * 128 + dcol) = v;
        }
    }
}

// ---------------------------------------------------------------------------
// Kernel 3: causal flash attention — R12/R13 version VERBATIM (verified
// 58.6-58.9 us, best measured; equilibrium robust to 9 perturbations).
// KVBLK=128 dbuf, hoisted staging offsets, 256 blocks x 512 thr, strips
// a & 15-a (uniform 17 iters), bh%8=XCD, cross-half reductions via
// permlane32_swap, per-strip LDS flash combine.  Dynamic LDS 131072 B.
// ---------------------------------------------------------------------------
__global__ __launch_bounds__(512, 2)
void attn_kernel(const short* __restrict__ qkv, float* __restrict__ out)
{
    extern __shared__ char smem[];
    const int tid = threadIdx.x, lane = tid & 63, wave = tid >> 6;
    const int l31 = lane & 31;
    const int hh_ = lane >> 5;

    const int bh = blockIdx.x & 31;             // bh%8 = XCD under round-robin
    const int a = blockIdx.x >> 5;              // 0..7

    const int qc = wave & 3;                    // q sub-block (32 rows)
    const int kvh = wave >> 2;                  // kv half of staged 128-kv tile

    const size_t HSTRIDE = (size_t)2048 * 128;
    const short* Kp = qkv + (size_t)bh * HSTRIDE;                    // [t][d]
    const short* Qp = qkv + (size_t)32 * HSTRIDE + (size_t)bh * HSTRIDE;
    const short* Vp = qkv + (size_t)64 * HSTRIDE + (size_t)bh * HSTRIDE; // [d][t]

    // ---- hoisted staging offsets (tid-only; computed once) ----------------
    int koffs[4], voffs[4];
#pragma unroll
    for (int i = 0; i < 4; ++i) {
        int c = i * 512 + tid;                  // 0..2047, 16B chunk index
        int rk = c >> 4;                        // K row 0..127
        int kof = (((c * 16) & 255) ^ ((rk & 15) << 4)) >> 1;
        koffs[i] = rk * 128 + kof;              // + j0*128 at stage time
        int sub = c >> 10, cc = c & 1023;       // V subtile, chunk within
        int rv = cc >> 4;                       // pair-row 0..63
        int pp = ((cc * 16) & 255) ^ ((rv & 15) << 4);
        int d = 2 * rv + (pp >> 7);
        int t = (pp & 127) >> 1;
        voffs[i] = d * 2048 + sub * 64 + t;     // + j0 at stage time
    }

#define STAGE128(J0, BUF) {                                                   \
        char* _b = smem + ((BUF) << 16);                                      \
        _Pragma("unroll")                                                     \
        for (int i_ = 0; i_ < 4; ++i_) {                                      \
            int c = i_ * 512 + tid;                                           \
            __builtin_amdgcn_global_load_lds(                                 \
                (const AS1 void*)(Kp + koffs[i_] + (J0) * 128),               \
                (AS3 void*)(_b + c * 16), 16, 0, 0);                          \
            __builtin_amdgcn_global_load_lds(                                 \
                (const AS1 void*)(Vp + voffs[i_] + (J0)),                     \
                (AS3 void*)(_b + 32768 + c * 16), 16, 0, 0);                  \
        }                                                                     \
    }

    for (int sidx = 0; sidx < 2; ++sidx) {
        const int sp = sidx ? (15 - a) : a;     // strip index 0..15
        const int q0 = sp * 128;
        const int nt = sp + 1;                  // 128-kv tiles
        const int qwave = q0 + qc * 32;
        const int qglob = qwave + l31;

        __syncthreads();                        // LDS free (prev combine done)

        // Q B-operand frags
        bf16x8 qf[8];
        {
            const short* qrow = Qp + (size_t)(q0 + qc * 32 + l31) * 128 + hh_ * 8;
#pragma unroll
            for (int dblk = 0; dblk < 8; ++dblk)
                qf[dblk] = *(const bf16x8*)(qrow + dblk * 16);
        }

        float mrow = -1e30f, lrow = 0.f;
        f32x16 acco[4] = {};                    // O[q(reg)][dt*32 + l31]

        STAGE128(0, 0);                         // prologue: tile 0 -> buf 0
        asm volatile("s_waitcnt vmcnt(0)" ::: "memory");
        __builtin_amdgcn_sched_barrier(0);
        __builtin_amdgcn_s_barrier();           // tile 0 visible to all waves
        __builtin_amdgcn_sched_barrier(0);

        for (int jt = 0; jt < nt; ++jt) {
            const int j0 = jt << 7;
            if (jt + 1 < nt)
                STAGE128((jt + 1) << 7, (jt + 1) & 1);

            const int kv0 = j0 + kvh * 64;      // this wave's 64-kv window
            if (kv0 <= qwave + 31) {            // wave-uniform causal gate
                const char* Kb = smem + ((jt & 1) << 16);
                const char* Vb = Kb + 32768 + (kvh << 14);   // sub = kvh

                // S'^T = K Q'^T : lane pair (l, l^32) holds S'[kv][q=l31]
                f32x16 sacc[2] = {};
                __builtin_amdgcn_s_setprio(1);
#pragma unroll
                for (int dblk = 0; dblk < 8; ++dblk) {
#pragma unroll
                    for (int kvt = 0; kvt < 2; ++kvt) {
                        int krow = kvh * 64 + kvt * 32 + l31;
                        bf16x8 kf = *(const bf16x8*)(Kb + krow * 256 +
                            ((dblk * 32 + hh_ * 16) ^ ((krow & 15) << 4)));
                        sacc[kvt] = MFMA32(kf, qf[dblk], sacc[kvt]);
                    }
                }
                __builtin_amdgcn_s_setprio(0);

                // causal mask: only the straddle tile
                if (kv0 + 63 > qwave) {
#pragma unroll
                    for (int kvt = 0; kvt < 2; ++kvt)
#pragma unroll
                        for (int r = 0; r < 16; ++r) {
                            int kvglob = kv0 + kvt * 32 + (r & 3) + 8 * (r >> 2) + 4 * hh_;
                            if (kvglob > qglob) sacc[kvt][r] = -1e30f;
                        }
                }

                // row max: in-lane tree + cross-half permlane (pure VALU)
                float pmax = -1e30f;
#pragma unroll
                for (int kvt = 0; kvt < 2; ++kvt)
#pragma unroll
                    for (int r = 0; r < 16; r += 4) {
                        float a2 = fmaxf(sacc[kvt][r], sacc[kvt][r + 1]);
                        float b2 = fmaxf(sacc[kvt][r + 2], sacc[kvt][r + 3]);
                        pmax = fmaxf(pmax, fmaxf(a2, b2));
                    }
                {
                    uint32_t pa_ = __builtin_bit_cast(uint32_t, pmax), xx_, yy_;
                    SWAP32(xx_, yy_, pa_, pa_);
                    pmax = fmaxf(__builtin_bit_cast(float, xx_),
                                 __builtin_bit_cast(float, yy_));
                }

                // defer-max: rescale only when max grew by > 8 nats
                if (!__all(pmax - mrow <= 11.5416f)) {
                    float mn = fmaxf(mrow, pmax);
                    float alpha = __builtin_amdgcn_exp2f(mrow - mn);
                    mrow = mn;
                    lrow *= alpha;
#pragma unroll
                    for (int r = 0; r < 16; ++r) {
                        float ar = __shfl(alpha, (r & 3) + 8 * (r >> 2) + 4 * hh_);
#pragma unroll
                        for (int dt = 0; dt < 4; ++dt) acco[dt][r] *= ar;
                    }
                }

                // P = exp2(S' - m'), row sum, pack to bf16 pairs
                float psum = 0.f;
                uint32_t pkA[2][4], pkB[2][4];
#pragma unroll
                for (int kvt = 0; kvt < 2; ++kvt)
#pragma unroll
                    for (int sg = 0; sg < 4; ++sg) {
                        float p0 = __builtin_amdgcn_exp2f(sacc[kvt][4 * sg + 0] - mrow);
                        float p1 = __builtin_amdgcn_exp2f(sacc[kvt][4 * sg + 1] - mrow);
                        float p2 = __builtin_amdgcn_exp2f(sacc[kvt][4 * sg + 2] - mrow);
                        float p3 = __builtin_amdgcn_exp2f(sacc[kvt][4 * sg + 3] - mrow);
                        psum += (p0 + p1) + (p2 + p3);
                        pkA[kvt][sg] = pack_bf16(p0, p1);
                        pkB[kvt][sg] = pack_bf16(p2, p3);
                    }
                {
                    uint32_t pa_ = __builtin_bit_cast(uint32_t, psum), xx_, yy_;
                    SWAP32(xx_, yy_, pa_, pa_);
                    psum = __builtin_bit_cast(float, xx_) +
                           __builtin_bit_cast(float, yy_);
                }
                lrow += psum;

                // O += P V  (P A-frags assembled via cross-half swaps)
                __builtin_amdgcn_s_setprio(1);
#pragma unroll
                for (int w = 0; w < 4; ++w) {   // 16-kv slot within 64-kv half
                    const int kvt = w >> 1, kbl = w & 1;
                    uint32_t r0, r1, r2, r3;
                    SWAP32(r0, r2, pkA[kvt][2 * kbl], pkA[kvt][2 * kbl + 1]);
                    SWAP32(r1, r3, pkB[kvt][2 * kbl], pkB[kvt][2 * kbl + 1]);
                    union { uint32_t u[4]; bf16x8 v; } pa;
                    pa.u[0] = r0; pa.u[1] = r1; pa.u[2] = r2; pa.u[3] = r3;
#pragma unroll
                    for (int dt = 0; dt < 4; ++dt) {
                        int d = dt * 32 + l31;
                        int r = d >> 1;
                        int inner = ((d & 1) << 7) + w * 32 + hh_ * 16;
                        bf16x8 vf = *(const bf16x8*)(Vb + r * 256 + (inner ^ ((r & 15) << 4)));
                        acco[dt] = MFMA32(pa.v, vf, acco[dt]);
                    }
                }
                __builtin_amdgcn_s_setprio(0);
            }

            if (jt + 1 < nt) {
                asm volatile("s_waitcnt vmcnt(0)" ::: "memory");  // tile jt+1 landed
                __builtin_amdgcn_sched_barrier(0);
                __builtin_amdgcn_s_barrier();   // publish tile jt+1, release buf
                __builtin_amdgcn_sched_barrier(0);
            }
        }

        // ---- intra-block flash combine: merge kv halves (waves w, w+4) ----
        __syncthreads();                        // all waves done reading LDS
        float* ex = (float*)smem;               // 4 chunks x 4096 f32 (64 KB)
        float* ml = (float*)(smem + 65536);     // 4 chunks x 64 x {m,l} (2 KB)
        if (kvh == 1) {
            float* dst = ex + qc * 4096;
#pragma unroll
            for (int dt = 0; dt < 4; ++dt)
#pragma unroll
                for (int r = 0; r < 16; ++r)
                    dst[(dt * 16 + r) * 64 + lane] = acco[dt][r];
            ml[qc * 128 + lane * 2 + 0] = mrow;
            ml[qc * 128 + lane * 2 + 1] = lrow;
        }
        __syncthreads();
        if (kvh == 0) {
            float m1 = ml[qc * 128 + lane * 2 + 0];
            float l1 = ml[qc * 128 + lane * 2 + 1];
            float M  = fmaxf(mrow, m1);
            float av = __builtin_amdgcn_exp2f(mrow - M);
            float bv = __builtin_amdgcn_exp2f(m1 - M);  // 0 if half empty
            float lf = lrow * av + l1 * bv;
            float sA = av / lf, sB = bv / lf;
            const float* src = ex + qc * 4096;
            const int bb = bh >> 3, hd = bh & 7;
#pragma unroll
            for (int r = 0; r < 16; ++r) {
                int ql = (r & 3) + 8 * (r >> 2) + 4 * hh_;
                float sa = __shfl(sA, ql);
                float sb = __shfl(sB, ql);
                int t = qwave + ql;
                float* o = out + (size_t)(bb * 2048 + t) * 1024 + hd * 128 + l31;
#pragma unroll
                for (int dt = 0; dt < 4; ++dt)
                    o[dt * 32] = acco[dt][r] * sa + src[(dt * 16 + r) * 64 + lane] * sb;
            }
        }
        // drain combine stores before next strip's staging/waits
        asm volatile("s_waitcnt vmcnt(0)" ::: "memory");
    }
#undef STAGE128
}

// ---------------------------------------------------------------------------
extern "C" void kernel_launch(void* const* d_in, const int* in_sizes, int n_in,
                              void* d_out, int out_size, void* d_ws, size_t ws_size,
                              hipStream_t stream) {
    const float* x  = (const float*)d_in[0];
    const float* w  = (const float*)d_in[1];
    const float* bK = (const float*)d_in[2];
    const float* bQ = (const float*)d_in[3];
    const float* bV = (const float*)d_in[4];

    // workspace layout (bytes): xb 8,388,608 | W 3,145,728 (uses 2,359,296) |
    // qkv 50,331,648
    short* xb  = (short*)d_ws;
    short* W   = (short*)((char*)d_ws + 8388608);
    short* qkv = (short*)((char*)d_ws + 8388608 + 3145728);
    float* out = (float*)d_out;

    // allow 128 KB dynamic LDS (idempotent; not a stream op, capture-safe)
    hipFuncSetAttribute((const void*)attn_kernel,
                        hipFuncAttributeMaxDynamicSharedMemorySize, 131072);

    prep_kernel<<<2048, 256, 0, stream>>>(x, w, bK, bQ, bV, xb, W);
    proj_gemm<<<1216, 256, 0, stream>>>(xb, W, qkv);
    attn_kernel<<<256, 512, 131072, stream>>>(qkv, out);
}